// Round 1
// baseline (1142.083 us; speedup 1.0000x reference)
//
#include <hip/hip_runtime.h>
#include <math.h>

#define N_NODES 20000
#define N_EDGES 320000
#define EPRIME  (N_EDGES + N_NODES)
#define NP      100000

static __device__ __forceinline__ float lrelu02(float v) {
    return v > 0.0f ? v : 0.2f * v;
}

// ---------------------------------------------------------------------------
// Generic 64x64 tiled fp32 GEMM.
// ASRC: 0 = A0[M,K] row-major
//       1 = concat(A0[M,256], A1[M,256])  (K==512)
//       2 = concat(A0[idxU[r]], A0[idxV[r]])  (pair gather, K==512)
// EPI:  0 = C = acc
//       1 = C = relu(acc + bias[col])
//       2 = outp[r] += sum_col relu(acc + bias[col]) * w2[col]   (atomic)
// ---------------------------------------------------------------------------
template<int ASRC, int EPI>
__global__ __launch_bounds__(256) void gemm_k(
    const float* __restrict__ A0, const float* __restrict__ A1,
    const int* __restrict__ idxU, const int* __restrict__ idxV,
    const float* __restrict__ B, const float* __restrict__ bias,
    const float* __restrict__ w2,
    float* __restrict__ C, float* __restrict__ outp,
    int M, int K, int Nn)
{
    __shared__ float As[16][68];
    __shared__ float Bs[16][68];

    const int tid = threadIdx.x;
    const int bm = blockIdx.x, bn = blockIdx.y;
    const int row0 = bm * 64, col0 = bn * 64;
    const int tx = tid & 15, ty = tid >> 4;

    float acc[4][4] = {};

    // A-tile load assignment: each thread loads 4 consecutive k for one row
    const int am  = tid >> 2;          // 0..63
    const int akq = (tid & 3) * 4;     // 0,4,8,12
    const int arow = row0 + am;
    const float* aptrL = nullptr;
    const float* aptrH = nullptr;
    if (arow < M) {
        if (ASRC == 0) {
            aptrL = A0 + (long)arow * K;
        } else if (ASRC == 1) {
            aptrL = A0 + (long)arow * 256;
            aptrH = A1 + (long)arow * 256;
        } else {
            const int u = idxU[arow], v = idxV[arow];
            aptrL = A0 + (long)u * 256;
            aptrH = A0 + (long)v * 256;
        }
    }
    // B-tile load assignment
    const int bk  = tid >> 4;          // 0..15
    const int bnq = (tid & 15) * 4;

    const int nK = K >> 4;
    for (int t = 0; t < nK; ++t) {
        const int k0 = t << 4;
        float4 av = make_float4(0.f, 0.f, 0.f, 0.f);
        if (arow < M) {
            const int kk = k0 + akq;
            const float* p;
            if (ASRC == 0) p = aptrL + kk;
            else           p = (kk < 256) ? (aptrL + kk) : (aptrH + (kk - 256));
            av = *(const float4*)p;
        }
        As[akq + 0][am] = av.x;
        As[akq + 1][am] = av.y;
        As[akq + 2][am] = av.z;
        As[akq + 3][am] = av.w;

        float4 bv = *(const float4*)(B + (long)(k0 + bk) * Nn + col0 + bnq);
        Bs[bk][bnq + 0] = bv.x;
        Bs[bk][bnq + 1] = bv.y;
        Bs[bk][bnq + 2] = bv.z;
        Bs[bk][bnq + 3] = bv.w;

        __syncthreads();
        #pragma unroll
        for (int k = 0; k < 16; ++k) {
            float a[4], b[4];
            #pragma unroll
            for (int i = 0; i < 4; ++i) a[i] = As[k][ty * 4 + i];
            #pragma unroll
            for (int j = 0; j < 4; ++j) b[j] = Bs[k][tx * 4 + j];
            #pragma unroll
            for (int i = 0; i < 4; ++i)
                #pragma unroll
                for (int j = 0; j < 4; ++j)
                    acc[i][j] = fmaf(a[i], b[j], acc[i][j]);
        }
        __syncthreads();
    }

    if constexpr (EPI == 0 || EPI == 1) {
        #pragma unroll
        for (int i = 0; i < 4; ++i) {
            const int r = row0 + ty * 4 + i;
            if (r < M) {
                #pragma unroll
                for (int j = 0; j < 4; ++j) {
                    const int c = col0 + tx * 4 + j;
                    float v = acc[i][j];
                    if constexpr (EPI == 1) {
                        v += bias[c];
                        v = v > 0.f ? v : 0.f;
                    }
                    C[(long)r * Nn + c] = v;
                }
            }
        }
    } else {
        // predictor epilogue: relu(acc + pb1) dot pw2, block-reduce, atomicAdd
        __shared__ float red[64][16];
        float s[4];
        #pragma unroll
        for (int i = 0; i < 4; ++i) {
            s[i] = 0.f;
            #pragma unroll
            for (int j = 0; j < 4; ++j) {
                const int c = col0 + tx * 4 + j;
                float v = acc[i][j] + bias[c];
                v = v > 0.f ? v : 0.f;
                s[i] += v * w2[c];
            }
        }
        #pragma unroll
        for (int i = 0; i < 4; ++i) red[ty * 4 + i][tx] = s[i];
        __syncthreads();
        if (tid < 64) {
            float tot = 0.f;
            #pragma unroll
            for (int q = 0; q < 16; ++q) tot += red[tid][q];
            const int r = row0 + tid;
            if (r < M) atomicAdd(outp + r, tot);
        }
    }
}

// ---------------------------------------------------------------------------
// alpha kernels: per-node attention logit pre-terms
// ---------------------------------------------------------------------------
__global__ __launch_bounds__(256) void alpha1_k(
    const float* __restrict__ h1, const float* __restrict__ a1s,
    const float* __restrict__ a1d, float* __restrict__ as1, float* __restrict__ ad1)
{
    const int wid = threadIdx.x >> 6;
    const int lane = threadIdx.x & 63;
    const int n = blockIdx.x * 4 + wid;
    if (n >= N_NODES) return;
    float ps[4], pd[4];
    #pragma unroll
    for (int h = 0; h < 4; ++h) {
        const float hv = h1[(long)n * 256 + h * 64 + lane];
        ps[h] = hv * a1s[h * 64 + lane];
        pd[h] = hv * a1d[h * 64 + lane];
    }
    #pragma unroll
    for (int off = 32; off > 0; off >>= 1) {
        #pragma unroll
        for (int h = 0; h < 4; ++h) {
            ps[h] += __shfl_xor(ps[h], off);
            pd[h] += __shfl_xor(pd[h], off);
        }
    }
    if (lane == 0) {
        #pragma unroll
        for (int h = 0; h < 4; ++h) {
            as1[n * 4 + h] = ps[h];
            ad1[n * 4 + h] = pd[h];
        }
    }
}

__global__ __launch_bounds__(256) void alpha2_k(
    const float* __restrict__ h2, const float* __restrict__ a2s,
    const float* __restrict__ a2d, float* __restrict__ as2, float* __restrict__ ad2)
{
    const int wid = threadIdx.x >> 6;
    const int lane = threadIdx.x & 63;
    const int n = blockIdx.x * 4 + wid;
    if (n >= N_NODES) return;
    float ps = 0.f, pd = 0.f;
    #pragma unroll
    for (int q = 0; q < 4; ++q) {
        const float hv = h2[(long)n * 256 + q * 64 + lane];
        ps += hv * a2s[q * 64 + lane];
        pd += hv * a2d[q * 64 + lane];
    }
    #pragma unroll
    for (int off = 32; off > 0; off >>= 1) {
        ps += __shfl_xor(ps, off);
        pd += __shfl_xor(pd, off);
    }
    if (lane == 0) { as2[n] = ps; ad2[n] = pd; }
}

// ---------------------------------------------------------------------------
// CSR construction (by dst, self-loops included via deg init = 1)
// ---------------------------------------------------------------------------
__global__ __launch_bounds__(256) void deg_init_k(int* __restrict__ deg)
{
    const int i = blockIdx.x * 256 + threadIdx.x;
    if (i < N_NODES) deg[i] = 1;   // self-loop
}

__global__ __launch_bounds__(256) void deg_count_k(const int* __restrict__ ei, int* __restrict__ deg)
{
    const int e = blockIdx.x * 256 + threadIdx.x;
    if (e < N_EDGES) atomicAdd(&deg[ei[N_EDGES + e]], 1);
}

__global__ __launch_bounds__(1024) void scan_k(const int* __restrict__ deg,
                                               int* __restrict__ indptr,
                                               int* __restrict__ pos)
{
    __shared__ int sums[1024];
    const int tid = threadIdx.x;
    const int CH = 20;                       // 1024*20 = 20480 >= 20000
    const int start = tid * CH;
    const int end = min(start + CH, N_NODES);
    int s = 0;
    for (int i = start; i < end; ++i) s += deg[i];
    sums[tid] = s;
    __syncthreads();
    for (int off = 1; off < 1024; off <<= 1) {
        const int v = sums[tid];
        const int add = (tid >= off) ? sums[tid - off] : 0;
        __syncthreads();
        sums[tid] = v + add;
        __syncthreads();
    }
    int pre = sums[tid] - s;                 // exclusive prefix
    for (int i = start; i < end; ++i) {
        indptr[i] = pre;
        pos[i] = pre;
        pre += deg[i];
    }
    if (tid == 1023) indptr[N_NODES] = sums[1023];
}

__global__ __launch_bounds__(256) void fill_k(const int* __restrict__ ei,
                                              int* __restrict__ pos, int* __restrict__ csr)
{
    const int i = blockIdx.x * 256 + threadIdx.x;
    if (i < N_EDGES) {
        const int s = ei[i], d = ei[N_EDGES + i];
        const int p = atomicAdd(&pos[d], 1);
        csr[p] = s;
    } else if (i < EPRIME) {
        const int n = i - N_EDGES;
        const int p = atomicAdd(&pos[n], 1);
        csr[p] = n;
    }
}

// ---------------------------------------------------------------------------
// GAT aggregation, conv1: 4 heads x 64 ch. One block per dst node.
// out[n,c] = elu( sum_e softmax_e(lrelu(as[src]+ad[n])) * h1[src,c] + b1[c] )
// ---------------------------------------------------------------------------
__global__ __launch_bounds__(256) void agg1_k(
    const float* __restrict__ h1, const float* __restrict__ as1,
    const float* __restrict__ ad1, const int* __restrict__ indptr,
    const int* __restrict__ csr, const float* __restrict__ b1,
    float* __restrict__ out)
{
    const int n = blockIdx.x;
    const int beg = indptr[n], end = indptr[n + 1];
    const int tid = threadIdx.x;
    __shared__ float red[256];
    __shared__ float mh[4], dh[4];
    __shared__ int   ssrc[64];
    __shared__ float sw[64][4];

    float ad[4];
    #pragma unroll
    for (int h = 0; h < 4; ++h) ad[h] = ad1[n * 4 + h];

    // pass 1: per-head max
    float lm[4] = {-1e30f, -1e30f, -1e30f, -1e30f};
    for (int e = beg + tid; e < end; e += 256) {
        const int s = csr[e];
        #pragma unroll
        for (int h = 0; h < 4; ++h)
            lm[h] = fmaxf(lm[h], lrelu02(as1[s * 4 + h] + ad[h]));
    }
    for (int h = 0; h < 4; ++h) {
        red[tid] = lm[h];
        __syncthreads();
        for (int s = 128; s > 0; s >>= 1) {
            if (tid < s) red[tid] = fmaxf(red[tid], red[tid + s]);
            __syncthreads();
        }
        if (tid == 0) mh[h] = red[0];
        __syncthreads();
    }
    // pass 2: per-head denom
    float ls[4] = {0.f, 0.f, 0.f, 0.f};
    for (int e = beg + tid; e < end; e += 256) {
        const int s = csr[e];
        #pragma unroll
        for (int h = 0; h < 4; ++h)
            ls[h] += expf(lrelu02(as1[s * 4 + h] + ad[h]) - mh[h]);
    }
    for (int h = 0; h < 4; ++h) {
        red[tid] = ls[h];
        __syncthreads();
        for (int s = 128; s > 0; s >>= 1) {
            if (tid < s) red[tid] += red[tid + s];
            __syncthreads();
        }
        if (tid == 0) dh[h] = red[0];
        __syncthreads();
    }
    // pass 3: weighted aggregation over channels
    const int c = tid, hd = tid >> 6;
    float acc = 0.f;
    for (int base = beg; base < end; base += 64) {
        const int cnt = min(64, end - base);
        if (tid < cnt) {
            const int s = csr[base + tid];
            ssrc[tid] = s;
            #pragma unroll
            for (int h = 0; h < 4; ++h)
                sw[tid][h] = expf(lrelu02(as1[s * 4 + h] + ad[h]) - mh[h]);
        }
        __syncthreads();
        for (int e = 0; e < cnt; ++e)
            acc += sw[e][hd] * h1[(long)ssrc[e] * 256 + c];
        __syncthreads();
    }
    float v = acc / dh[hd] + b1[c];
    out[(long)n * 256 + c] = v > 0.f ? v : (expf(v) - 1.0f);   // ELU
}

// conv2: 1 head x 256 ch, no activation, +b2
__global__ __launch_bounds__(256) void agg2_k(
    const float* __restrict__ h2, const float* __restrict__ as2,
    const float* __restrict__ ad2, const int* __restrict__ indptr,
    const int* __restrict__ csr, const float* __restrict__ b2,
    float* __restrict__ out)
{
    const int n = blockIdx.x;
    const int beg = indptr[n], end = indptr[n + 1];
    const int tid = threadIdx.x;
    __shared__ float red[256];
    __shared__ float msh, dsh;
    __shared__ int   ssrc[64];
    __shared__ float sw[64];

    const float adv = ad2[n];

    float lm = -1e30f;
    for (int e = beg + tid; e < end; e += 256)
        lm = fmaxf(lm, lrelu02(as2[csr[e]] + adv));
    red[tid] = lm;
    __syncthreads();
    for (int s = 128; s > 0; s >>= 1) {
        if (tid < s) red[tid] = fmaxf(red[tid], red[tid + s]);
        __syncthreads();
    }
    if (tid == 0) msh = red[0];
    __syncthreads();
    const float m = msh;

    float lsum = 0.f;
    for (int e = beg + tid; e < end; e += 256)
        lsum += expf(lrelu02(as2[csr[e]] + adv) - m);
    red[tid] = lsum;
    __syncthreads();
    for (int s = 128; s > 0; s >>= 1) {
        if (tid < s) red[tid] += red[tid + s];
        __syncthreads();
    }
    if (tid == 0) dsh = red[0];
    __syncthreads();
    const float d = dsh;

    const int c = tid;
    float acc = 0.f;
    for (int base = beg; base < end; base += 64) {
        const int cnt = min(64, end - base);
        if (tid < cnt) {
            const int s = csr[base + tid];
            ssrc[tid] = s;
            sw[tid] = expf(lrelu02(as2[s] + adv) - m);
        }
        __syncthreads();
        for (int e = 0; e < cnt; ++e)
            acc += sw[e] * h2[(long)ssrc[e] * 256 + c];
        __syncthreads();
    }
    out[(long)n * 256 + c] = acc / d + b2[c];
}

// ---------------------------------------------------------------------------
// gate finalize: g = sigmoid(ghid . gw2 + gb2); hf = (1-g)*x + g*hg (in-place hg)
// ---------------------------------------------------------------------------
__global__ __launch_bounds__(256) void gatefin_k(
    const float* __restrict__ ghid, const float* __restrict__ gw2,
    const float* __restrict__ gb2, const float* __restrict__ x,
    float* __restrict__ hg)
{
    const int wid = threadIdx.x >> 6;
    const int lane = threadIdx.x & 63;
    const int n = blockIdx.x * 4 + wid;
    if (n >= N_NODES) return;
    float s = 0.f;
    #pragma unroll
    for (int q = 0; q < 4; ++q)
        s += ghid[(long)n * 256 + q * 64 + lane] * gw2[q * 64 + lane];
    #pragma unroll
    for (int off = 32; off > 0; off >>= 1) s += __shfl_xor(s, off);
    const float g = 1.0f / (1.0f + expf(-(s + gb2[0])));
    #pragma unroll
    for (int q = 0; q < 4; ++q) {
        const int c = q * 64 + lane;
        const float xv = x[(long)n * 256 + c];
        const float hv = hg[(long)n * 256 + c];
        hg[(long)n * 256 + c] = (1.0f - g) * xv + g * hv;
    }
}

__global__ __launch_bounds__(256) void outinit_k(float* __restrict__ out, const float* __restrict__ pb2)
{
    const int p = blockIdx.x * 256 + threadIdx.x;
    if (p < NP) out[p] = pb2[0];
}

// ---------------------------------------------------------------------------
extern "C" void kernel_launch(void* const* d_in, const int* in_sizes, int n_in,
                              void* d_out, int out_size, void* d_ws, size_t ws_size,
                              hipStream_t stream)
{
    const float* x   = (const float*)d_in[0];
    const int*   ei  = (const int*)d_in[1];
    const int*   un  = (const int*)d_in[2];
    const int*   vn  = (const int*)d_in[3];
    const float* W1  = (const float*)d_in[4];
    const float* a1s = (const float*)d_in[5];
    const float* a1d = (const float*)d_in[6];
    const float* b1  = (const float*)d_in[7];
    const float* W2  = (const float*)d_in[8];
    const float* a2s = (const float*)d_in[9];
    const float* a2d = (const float*)d_in[10];
    const float* b2  = (const float*)d_in[11];
    const float* gw1 = (const float*)d_in[12];
    const float* gb1 = (const float*)d_in[13];
    const float* gw2 = (const float*)d_in[14];
    const float* gb2 = (const float*)d_in[15];
    const float* pw1 = (const float*)d_in[16];
    const float* pb1 = (const float*)d_in[17];
    const float* pw2 = (const float*)d_in[18];
    const float* pb2 = (const float*)d_in[19];
    float* out = (float*)d_out;

    // workspace layout (f32 elements)
    float* bufA = (float*)d_ws;             // h1 -> h2 -> ghid
    float* bufB = bufA + 5120000;           // h1a -> hg -> hf (in place)
    float* as1v = bufB + 5120000;
    float* ad1v = as1v + 80000;
    float* as2v = ad1v + 80000;
    float* ad2v = as2v + 20000;
    int* deg    = (int*)(ad2v + 20000);
    int* indptr = deg + 20000;
    int* pos    = indptr + 20032;
    int* csr    = pos + 20000;
    if (ws_size < 46u * 1024u * 1024u) return;   // need ~43.3 MB

    dim3 b256(256);

    // CSR build (independent of GEMM1)
    deg_init_k<<<(N_NODES + 255) / 256, b256, 0, stream>>>(deg);
    deg_count_k<<<(N_EDGES + 255) / 256, b256, 0, stream>>>(ei, deg);
    scan_k<<<1, 1024, 0, stream>>>(deg, indptr, pos);
    fill_k<<<(EPRIME + 255) / 256, b256, 0, stream>>>(ei, pos, csr);

    // conv1
    gemm_k<0, 0><<<dim3(313, 4), b256, 0, stream>>>(
        x, nullptr, nullptr, nullptr, W1, nullptr, nullptr, bufA, nullptr,
        N_NODES, 256, 256);
    alpha1_k<<<5000, b256, 0, stream>>>(bufA, a1s, a1d, as1v, ad1v);
    agg1_k<<<N_NODES, b256, 0, stream>>>(bufA, as1v, ad1v, indptr, csr, b1, bufB);

    // conv2
    gemm_k<0, 0><<<dim3(313, 4), b256, 0, stream>>>(
        bufB, nullptr, nullptr, nullptr, W2, nullptr, nullptr, bufA, nullptr,
        N_NODES, 256, 256);
    alpha2_k<<<5000, b256, 0, stream>>>(bufA, a2s, a2d, as2v, ad2v);
    agg2_k<<<N_NODES, b256, 0, stream>>>(bufA, as2v, ad2v, indptr, csr, b2, bufB);

    // gate MLP: ghid = relu(concat(x, hg) @ gw1 + gb1)
    gemm_k<1, 1><<<dim3(313, 4), b256, 0, stream>>>(
        x, bufB, nullptr, nullptr, gw1, gb1, nullptr, bufA, nullptr,
        N_NODES, 512, 256);
    gatefin_k<<<5000, b256, 0, stream>>>(bufA, gw2, gb2, x, bufB);

    // predictor: out[p] = relu(concat(hf[u],hf[v]) @ pw1 + pb1) . pw2 + pb2
    outinit_k<<<(NP + 255) / 256, b256, 0, stream>>>(out, pb2);
    gemm_k<2, 2><<<dim3(1563, 8), b256, 0, stream>>>(
        bufB, nullptr, un, vn, pw1, pb1, pw2, nullptr, out,
        NP, 512, 512);
}

// Round 2
// 402.100 us; speedup vs baseline: 2.8403x; 2.8403x over previous
//
#include <hip/hip_runtime.h>
#include <math.h>

#define N_NODES 20000
#define N_EDGES 320000
#define EPRIME  (N_EDGES + N_NODES)
#define NP      100000

typedef __bf16 bf16x8 __attribute__((ext_vector_type(8)));
typedef float  f32x4  __attribute__((ext_vector_type(4)));

__device__ __forceinline__ float b2f(unsigned short u) {
    union { float f; unsigned int v; } x; x.v = ((unsigned int)u) << 16; return x.f;
}
__device__ __forceinline__ unsigned short f2b(float f) {
    union { float f; unsigned int v; } x; x.f = f;
    unsigned int r = (x.v + 0x7fffu + ((x.v >> 16) & 1u)) >> 16;
    return (unsigned short)r;
}
__device__ __forceinline__ float lrelu02(float v) { return v > 0.0f ? v : 0.2f * v; }

__device__ __forceinline__ void gload16(const void* g, void* l) {
    __builtin_amdgcn_global_load_lds(
        (const __attribute__((address_space(1))) void*)g,
        (__attribute__((address_space(3))) void*)l, 16, 0, 0);
}

// ---------------------------------------------------------------------------
// bf16 MFMA GEMM, 128x128 tile, BK=32, 4 waves (2x2 of 64x64), dbuf LDS.
// A is bf16 [M,K]-like (see ASRC), BT is bf16 [Nn][K] (pre-transposed B).
// ASRC: 0 = A0[M,K]; 1 = concat(A0[M,256],A1[M,256]) K=512;
//       2 = concat(A0[idxU[r]],A0[idxV[r]]) K=512 (pair gather)
// EPI:  0 = Cb = bf16(acc); 1 = Cb = bf16(relu(acc+bias[col]));
//       2 = outp[row] += sum_col relu(acc+bias[col])*w2[col]  (atomic)
// ---------------------------------------------------------------------------
template<int ASRC, int EPI>
__global__ __launch_bounds__(256) void mgemm_k(
    const unsigned short* __restrict__ A0, const unsigned short* __restrict__ A1,
    const int* __restrict__ idxU, const int* __restrict__ idxV,
    const unsigned short* __restrict__ BT,
    const float* __restrict__ bias, const float* __restrict__ w2,
    unsigned short* __restrict__ Cb, float* __restrict__ outp,
    int M, int K, int Nn)
{
    __shared__ unsigned short As[2][4096];   // [128 rows][32 k] bf16
    __shared__ unsigned short Bs[2][4096];   // [128 cols][32 k] bf16

    const int tid = threadIdx.x;
    const int wave = tid >> 6, lane = tid & 63;
    const int row0 = blockIdx.x * 128, col0 = blockIdx.y * 128;
    const int ksub = (lane & 3) * 8;         // bf16 offset of this lane's 16B chunk

    // staging: thread covers 2 rows (j=0,1); row r = j*64 + wave*16 + lane>>2
    const unsigned short* aL[2];
    const unsigned short* aH[2];
    const unsigned short* bP[2];
    #pragma unroll
    for (int j = 0; j < 2; ++j) {
        const int r = j * 64 + wave * 16 + (lane >> 2);
        int ar = row0 + r; if (ar > M - 1) ar = M - 1;   // clamp: guarded at store
        if (ASRC == 0)      { aL[j] = A0 + (long)ar * K;  aH[j] = aL[j]; }
        else if (ASRC == 1) { aL[j] = A0 + (long)ar * 256; aH[j] = A1 + (long)ar * 256; }
        else { const int u = idxU[ar], v = idxV[ar];
               aL[j] = A0 + (long)u * 256;  aH[j] = A0 + (long)v * 256; }
        bP[j] = BT + (long)(col0 + r) * K;   // Nn is a multiple of 128: no guard
    }

    const int wm = wave >> 1, wn = wave & 1;
    const int lrow = lane & 15, lk = (lane >> 4) * 8;

    f32x4 acc[4][4] = {};

    const int nT = K >> 5;
    int buf = 0;

    auto stage = [&](int bi, int t) {
        const int k0 = t << 5;
        #pragma unroll
        for (int j = 0; j < 2; ++j) {
            const unsigned short* ga;
            if (ASRC == 0) ga = aL[j] + k0 + ksub;
            else ga = (k0 < 256) ? (aL[j] + k0 + ksub) : (aH[j] + (k0 - 256) + ksub);
            const int ci = j * 256 + wave * 64 + lane;   // linear 16B-chunk index
            gload16(ga, &As[bi][ci * 8]);
            gload16(bP[j] + k0 + ksub, &Bs[bi][ci * 8]);
        }
    };

    stage(0, 0);
    __syncthreads();
    for (int t = 0; t < nT; ++t) {
        if (t + 1 < nT) stage(buf ^ 1, t + 1);   // prefetch overlaps this tile's MFMA
        bf16x8 a[4], b[4];
        #pragma unroll
        for (int i = 0; i < 4; ++i)
            a[i] = *(const bf16x8*)&As[buf][(wm * 64 + i * 16 + lrow) * 32 + lk];
        #pragma unroll
        for (int j = 0; j < 4; ++j)
            b[j] = *(const bf16x8*)&Bs[buf][(wn * 64 + j * 16 + lrow) * 32 + lk];
        #pragma unroll
        for (int i = 0; i < 4; ++i)
            #pragma unroll
            for (int j = 0; j < 4; ++j)
                acc[i][j] = __builtin_amdgcn_mfma_f32_16x16x32_bf16(a[i], b[j], acc[i][j], 0, 0, 0);
        __syncthreads();
        buf ^= 1;
    }

    if constexpr (EPI == 0 || EPI == 1) {
        #pragma unroll
        for (int i = 0; i < 4; ++i) {
            #pragma unroll
            for (int p = 0; p < 4; ++p) {
                const int row = row0 + wm * 64 + i * 16 + (lane >> 4) * 4 + p;
                if (row < M) {
                    #pragma unroll
                    for (int j = 0; j < 4; ++j) {
                        const int col = col0 + wn * 64 + j * 16 + (lane & 15);
                        float v = acc[i][j][p];
                        if (EPI == 1) { v += bias[col]; v = v > 0.f ? v : 0.f; }
                        Cb[(long)row * Nn + col] = f2b(v);
                    }
                }
            }
        }
    } else {
        float s[4][4];
        #pragma unroll
        for (int i = 0; i < 4; ++i) {
            #pragma unroll
            for (int p = 0; p < 4; ++p) {
                float t = 0.f;
                #pragma unroll
                for (int j = 0; j < 4; ++j) {
                    const int col = col0 + wn * 64 + j * 16 + (lane & 15);
                    float v = acc[i][j][p] + bias[col];
                    v = v > 0.f ? v : 0.f;
                    t += v * w2[col];
                }
                s[i][p] = t;
            }
        }
        #pragma unroll
        for (int off = 1; off < 16; off <<= 1) {
            #pragma unroll
            for (int i = 0; i < 4; ++i)
                #pragma unroll
                for (int p = 0; p < 4; ++p)
                    s[i][p] += __shfl_xor(s[i][p], off);
        }
        if ((lane & 15) == 0) {
            #pragma unroll
            for (int i = 0; i < 4; ++i)
                #pragma unroll
                for (int p = 0; p < 4; ++p) {
                    const int row = row0 + wm * 64 + i * 16 + (lane >> 4) * 4 + p;
                    if (row < M) atomicAdd(outp + row, s[i][p]);
                }
        }
    }
}

// ---------------------------------------------------------------------------
// small prep kernels
// ---------------------------------------------------------------------------
__global__ __launch_bounds__(256) void castx_k(const float* __restrict__ x,
                                               unsigned short* __restrict__ xb)
{
    const int id = blockIdx.x * 256 + threadIdx.x;   // 1.28M float4s
    const float4 v = ((const float4*)x)[id];
    ushort4 o;
    o.x = f2b(v.x); o.y = f2b(v.y); o.z = f2b(v.z); o.w = f2b(v.w);
    ((ushort4*)xb)[id] = o;
}

// BT[n*K+k] = bf16(B[k*N+n]); launched with K*N/256 blocks
__global__ __launch_bounds__(256) void tr_k(const float* __restrict__ B,
                                            unsigned short* __restrict__ BT,
                                            int K, int N)
{
    const int id = blockIdx.x * 256 + threadIdx.x;
    const int k = id / N, n = id % N;
    BT[(long)n * K + k] = f2b(B[id]);
}

// ---------------------------------------------------------------------------
// alpha kernels (bf16 h inputs)
// ---------------------------------------------------------------------------
__global__ __launch_bounds__(256) void alpha1_k(
    const unsigned short* __restrict__ h1, const float* __restrict__ a1s,
    const float* __restrict__ a1d, float* __restrict__ as1, float* __restrict__ ad1)
{
    const int wid = threadIdx.x >> 6;
    const int lane = threadIdx.x & 63;
    const int n = blockIdx.x * 4 + wid;
    if (n >= N_NODES) return;
    float ps[4], pd[4];
    #pragma unroll
    for (int h = 0; h < 4; ++h) {
        const float hv = b2f(h1[(long)n * 256 + h * 64 + lane]);
        ps[h] = hv * a1s[h * 64 + lane];
        pd[h] = hv * a1d[h * 64 + lane];
    }
    #pragma unroll
    for (int off = 32; off > 0; off >>= 1) {
        #pragma unroll
        for (int h = 0; h < 4; ++h) {
            ps[h] += __shfl_xor(ps[h], off);
            pd[h] += __shfl_xor(pd[h], off);
        }
    }
    if (lane == 0) {
        #pragma unroll
        for (int h = 0; h < 4; ++h) {
            as1[n * 4 + h] = ps[h];
            ad1[n * 4 + h] = pd[h];
        }
    }
}

__global__ __launch_bounds__(256) void alpha2_k(
    const unsigned short* __restrict__ h2, const float* __restrict__ a2s,
    const float* __restrict__ a2d, float* __restrict__ as2, float* __restrict__ ad2)
{
    const int wid = threadIdx.x >> 6;
    const int lane = threadIdx.x & 63;
    const int n = blockIdx.x * 4 + wid;
    if (n >= N_NODES) return;
    float ps = 0.f, pd = 0.f;
    #pragma unroll
    for (int q = 0; q < 4; ++q) {
        const float hv = b2f(h2[(long)n * 256 + q * 64 + lane]);
        ps += hv * a2s[q * 64 + lane];
        pd += hv * a2d[q * 64 + lane];
    }
    #pragma unroll
    for (int off = 32; off > 0; off >>= 1) {
        ps += __shfl_xor(ps, off);
        pd += __shfl_xor(pd, off);
    }
    if (lane == 0) { as2[n] = ps; ad2[n] = pd; }
}

// ---------------------------------------------------------------------------
// CSR construction (by dst, self-loops via deg init = 1)
// ---------------------------------------------------------------------------
__global__ __launch_bounds__(256) void deg_init_k(int* __restrict__ deg)
{
    const int i = blockIdx.x * 256 + threadIdx.x;
    if (i < N_NODES) deg[i] = 1;
}

__global__ __launch_bounds__(256) void deg_count_k(const int* __restrict__ ei, int* __restrict__ deg)
{
    const int e = blockIdx.x * 256 + threadIdx.x;
    if (e < N_EDGES) atomicAdd(&deg[ei[N_EDGES + e]], 1);
}

__global__ __launch_bounds__(1024) void scan_k(const int* __restrict__ deg,
                                               int* __restrict__ indptr,
                                               int* __restrict__ pos)
{
    __shared__ int sums[1024];
    const int tid = threadIdx.x;
    const int CH = 20;
    const int start = tid * CH;
    const int end = min(start + CH, N_NODES);
    int s = 0;
    for (int i = start; i < end; ++i) s += deg[i];
    sums[tid] = s;
    __syncthreads();
    for (int off = 1; off < 1024; off <<= 1) {
        const int v = sums[tid];
        const int add = (tid >= off) ? sums[tid - off] : 0;
        __syncthreads();
        sums[tid] = v + add;
        __syncthreads();
    }
    int pre = sums[tid] - s;
    for (int i = start; i < end; ++i) {
        indptr[i] = pre;
        pos[i] = pre;
        pre += deg[i];
    }
    if (tid == 1023) indptr[N_NODES] = sums[1023];
}

__global__ __launch_bounds__(256) void fill_k(const int* __restrict__ ei,
                                              int* __restrict__ pos, int* __restrict__ csr)
{
    const int i = blockIdx.x * 256 + threadIdx.x;
    if (i < N_EDGES) {
        const int s = ei[i], d = ei[N_EDGES + i];
        const int p = atomicAdd(&pos[d], 1);
        csr[p] = s;
    } else if (i < EPRIME) {
        const int n = i - N_EDGES;
        const int p = atomicAdd(&pos[n], 1);
        csr[p] = n;
    }
}

// ---------------------------------------------------------------------------
// GAT aggregation, conv1: 4 heads x 64 ch; reads bf16 h1, writes bf16 ELU out
// ---------------------------------------------------------------------------
__global__ __launch_bounds__(256) void agg1_k(
    const unsigned short* __restrict__ h1, const float* __restrict__ as1,
    const float* __restrict__ ad1, const int* __restrict__ indptr,
    const int* __restrict__ csr, const float* __restrict__ b1,
    unsigned short* __restrict__ out)
{
    const int n = blockIdx.x;
    const int beg = indptr[n], end = indptr[n + 1];
    const int tid = threadIdx.x;
    __shared__ float red[256];
    __shared__ float mh[4], dh[4];
    __shared__ int   ssrc[64];
    __shared__ float sw[64][4];

    float ad[4];
    #pragma unroll
    for (int h = 0; h < 4; ++h) ad[h] = ad1[n * 4 + h];

    float lm[4] = {-1e30f, -1e30f, -1e30f, -1e30f};
    for (int e = beg + tid; e < end; e += 256) {
        const int s = csr[e];
        #pragma unroll
        for (int h = 0; h < 4; ++h)
            lm[h] = fmaxf(lm[h], lrelu02(as1[s * 4 + h] + ad[h]));
    }
    for (int h = 0; h < 4; ++h) {
        red[tid] = lm[h];
        __syncthreads();
        for (int s = 128; s > 0; s >>= 1) {
            if (tid < s) red[tid] = fmaxf(red[tid], red[tid + s]);
            __syncthreads();
        }
        if (tid == 0) mh[h] = red[0];
        __syncthreads();
    }
    float ls[4] = {0.f, 0.f, 0.f, 0.f};
    for (int e = beg + tid; e < end; e += 256) {
        const int s = csr[e];
        #pragma unroll
        for (int h = 0; h < 4; ++h)
            ls[h] += expf(lrelu02(as1[s * 4 + h] + ad[h]) - mh[h]);
    }
    for (int h = 0; h < 4; ++h) {
        red[tid] = ls[h];
        __syncthreads();
        for (int s = 128; s > 0; s >>= 1) {
            if (tid < s) red[tid] += red[tid + s];
            __syncthreads();
        }
        if (tid == 0) dh[h] = red[0];
        __syncthreads();
    }
    const int c = tid, hd = tid >> 6;
    float acc = 0.f;
    for (int base = beg; base < end; base += 64) {
        const int cnt = min(64, end - base);
        if (tid < cnt) {
            const int s = csr[base + tid];
            ssrc[tid] = s;
            #pragma unroll
            for (int h = 0; h < 4; ++h)
                sw[tid][h] = expf(lrelu02(as1[s * 4 + h] + ad[h]) - mh[h]);
        }
        __syncthreads();
        for (int e = 0; e < cnt; ++e)
            acc += sw[e][hd] * b2f(h1[(long)ssrc[e] * 256 + c]);
        __syncthreads();
    }
    float v = acc / dh[hd] + b1[c];
    out[(long)n * 256 + c] = f2b(v > 0.f ? v : (expf(v) - 1.0f));
}

// conv2: 1 head x 256 ch, +b2, bf16 in/out
__global__ __launch_bounds__(256) void agg2_k(
    const unsigned short* __restrict__ h2, const float* __restrict__ as2,
    const float* __restrict__ ad2, const int* __restrict__ indptr,
    const int* __restrict__ csr, const float* __restrict__ b2,
    unsigned short* __restrict__ outb)
{
    const int n = blockIdx.x;
    const int beg = indptr[n], end = indptr[n + 1];
    const int tid = threadIdx.x;
    __shared__ float red[256];
    __shared__ float msh, dsh;
    __shared__ int   ssrc[64];
    __shared__ float sw[64];

    const float adv = ad2[n];

    float lm = -1e30f;
    for (int e = beg + tid; e < end; e += 256)
        lm = fmaxf(lm, lrelu02(as2[csr[e]] + adv));
    red[tid] = lm;
    __syncthreads();
    for (int s = 128; s > 0; s >>= 1) {
        if (tid < s) red[tid] = fmaxf(red[tid], red[tid + s]);
        __syncthreads();
    }
    if (tid == 0) msh = red[0];
    __syncthreads();
    const float m = msh;

    float lsum = 0.f;
    for (int e = beg + tid; e < end; e += 256)
        lsum += expf(lrelu02(as2[csr[e]] + adv) - m);
    red[tid] = lsum;
    __syncthreads();
    for (int s = 128; s > 0; s >>= 1) {
        if (tid < s) red[tid] += red[tid + s];
        __syncthreads();
    }
    if (tid == 0) dsh = red[0];
    __syncthreads();
    const float d = dsh;

    const int c = tid;
    float acc = 0.f;
    for (int base = beg; base < end; base += 64) {
        const int cnt = min(64, end - base);
        if (tid < cnt) {
            const int s = csr[base + tid];
            ssrc[tid] = s;
            sw[tid] = expf(lrelu02(as2[s] + adv) - m);
        }
        __syncthreads();
        for (int e = 0; e < cnt; ++e)
            acc += sw[e] * b2f(h2[(long)ssrc[e] * 256 + c]);
        __syncthreads();
    }
    outb[(long)n * 256 + c] = f2b(acc / d + b2[c]);
}

// ---------------------------------------------------------------------------
// gate finalize: g = sigmoid(ghid.gw2 + gb2); hf = (1-g)*x + g*hg  (bf16 out)
// ---------------------------------------------------------------------------
__global__ __launch_bounds__(256) void gatefin_k(
    const unsigned short* __restrict__ ghid, const float* __restrict__ gw2,
    const float* __restrict__ gb2, const float* __restrict__ x,
    const unsigned short* __restrict__ hgb, unsigned short* __restrict__ hfb)
{
    const int wid = threadIdx.x >> 6;
    const int lane = threadIdx.x & 63;
    const int n = blockIdx.x * 4 + wid;
    if (n >= N_NODES) return;
    float s = 0.f;
    #pragma unroll
    for (int q = 0; q < 4; ++q)
        s += b2f(ghid[(long)n * 256 + q * 64 + lane]) * gw2[q * 64 + lane];
    #pragma unroll
    for (int off = 32; off > 0; off >>= 1) s += __shfl_xor(s, off);
    const float g = 1.0f / (1.0f + expf(-(s + gb2[0])));
    #pragma unroll
    for (int q = 0; q < 4; ++q) {
        const int c = q * 64 + lane;
        const float xv = x[(long)n * 256 + c];
        const float hv = b2f(hgb[(long)n * 256 + c]);
        hfb[(long)n * 256 + c] = f2b((1.0f - g) * xv + g * hv);
    }
}

__global__ __launch_bounds__(256) void outinit_k(float* __restrict__ out, const float* __restrict__ pb2)
{
    const int p = blockIdx.x * 256 + threadIdx.x;
    if (p < NP) out[p] = pb2[0];
}

// ---------------------------------------------------------------------------
extern "C" void kernel_launch(void* const* d_in, const int* in_sizes, int n_in,
                              void* d_out, int out_size, void* d_ws, size_t ws_size,
                              hipStream_t stream)
{
    const float* x   = (const float*)d_in[0];
    const int*   ei  = (const int*)d_in[1];
    const int*   un  = (const int*)d_in[2];
    const int*   vn  = (const int*)d_in[3];
    const float* W1  = (const float*)d_in[4];
    const float* a1s = (const float*)d_in[5];
    const float* a1d = (const float*)d_in[6];
    const float* b1  = (const float*)d_in[7];
    const float* W2  = (const float*)d_in[8];
    const float* a2s = (const float*)d_in[9];
    const float* a2d = (const float*)d_in[10];
    const float* b2  = (const float*)d_in[11];
    const float* gw1 = (const float*)d_in[12];
    const float* gb1 = (const float*)d_in[13];
    const float* gw2 = (const float*)d_in[14];
    const float* gb2 = (const float*)d_in[15];
    const float* pw1 = (const float*)d_in[16];
    const float* pb1 = (const float*)d_in[17];
    const float* pw2 = (const float*)d_in[18];
    const float* pb2 = (const float*)d_in[19];
    float* out = (float*)d_out;

    // workspace layout
    unsigned short* bufHb = (unsigned short*)d_ws;        // h1b / h2b / ghidb
    unsigned short* h1ab  = bufHb + 5120000;              // agg1 out; later hfb
    unsigned short* hgb   = h1ab + 5120000;
    unsigned short* xb    = hgb + 5120000;
    unsigned short* W1t   = xb + 5120000;
    unsigned short* W2t   = W1t + 65536;
    unsigned short* gw1t  = W2t + 65536;
    unsigned short* pw1t  = gw1t + 131072;
    float* as1v = (float*)(pw1t + 262144);
    float* ad1v = as1v + 80000;
    float* as2v = ad1v + 80000;
    float* ad2v = as2v + 20000;
    int* deg    = (int*)(ad2v + 20000);
    int* indptr = deg + 20000;
    int* pos    = indptr + 20032;
    int* csr    = pos + 20000;
    if (ws_size < 46u * 1024u * 1024u) return;

    dim3 b256(256);

    // prep: casts + weight transposes + CSR (all independent)
    castx_k<<<5000, b256, 0, stream>>>(x, xb);
    tr_k<<<65536 / 256, b256, 0, stream>>>(W1, W1t, 256, 256);
    tr_k<<<65536 / 256, b256, 0, stream>>>(W2, W2t, 256, 256);
    tr_k<<<131072 / 256, b256, 0, stream>>>(gw1, gw1t, 512, 256);
    tr_k<<<262144 / 256, b256, 0, stream>>>(pw1, pw1t, 512, 512);
    deg_init_k<<<(N_NODES + 255) / 256, b256, 0, stream>>>(deg);
    deg_count_k<<<(N_EDGES + 255) / 256, b256, 0, stream>>>(ei, deg);
    scan_k<<<1, 1024, 0, stream>>>(deg, indptr, pos);
    fill_k<<<(EPRIME + 255) / 256, b256, 0, stream>>>(ei, pos, csr);

    // conv1: h1b = xb @ W1
    mgemm_k<0, 0><<<dim3(157, 2), b256, 0, stream>>>(
        xb, nullptr, nullptr, nullptr, W1t, nullptr, nullptr, bufHb, nullptr,
        N_NODES, 256, 256);
    alpha1_k<<<5000, b256, 0, stream>>>(bufHb, a1s, a1d, as1v, ad1v);
    agg1_k<<<N_NODES, b256, 0, stream>>>(bufHb, as1v, ad1v, indptr, csr, b1, h1ab);

    // conv2: h2b = h1a @ W2
    mgemm_k<0, 0><<<dim3(157, 2), b256, 0, stream>>>(
        h1ab, nullptr, nullptr, nullptr, W2t, nullptr, nullptr, bufHb, nullptr,
        N_NODES, 256, 256);
    alpha2_k<<<5000, b256, 0, stream>>>(bufHb, a2s, a2d, as2v, ad2v);
    agg2_k<<<N_NODES, b256, 0, stream>>>(bufHb, as2v, ad2v, indptr, csr, b2, hgb);

    // gate MLP hidden: ghidb = relu(concat(xb,hgb) @ gw1 + gb1)
    mgemm_k<1, 1><<<dim3(157, 2), b256, 0, stream>>>(
        xb, hgb, nullptr, nullptr, gw1t, gb1, nullptr, bufHb, nullptr,
        N_NODES, 512, 256);
    gatefin_k<<<5000, b256, 0, stream>>>(bufHb, gw2, gb2, x, hgb, h1ab);

    // predictor
    outinit_k<<<(NP + 255) / 256, b256, 0, stream>>>(out, pb2);
    mgemm_k<2, 2><<<dim3(782, 4), b256, 0, stream>>>(
        h1ab, nullptr, un, vn, pw1t, pb1, pw2, nullptr, out,
        NP, 512, 512);
}

// Round 3
// 292.747 us; speedup vs baseline: 3.9013x; 1.3735x over previous
//
#include <hip/hip_runtime.h>
#include <math.h>

#define N_NODES 20000
#define N_EDGES 320000
#define EPRIME  (N_EDGES + N_NODES)
#define NP      100000

typedef __bf16 bf16x8 __attribute__((ext_vector_type(8)));
typedef float  f32x4  __attribute__((ext_vector_type(4)));

__device__ __forceinline__ float b2f(unsigned short u) {
    union { float f; unsigned int v; } x; x.v = ((unsigned int)u) << 16; return x.f;
}
__device__ __forceinline__ unsigned short f2b(float f) {
    union { float f; unsigned int v; } x; x.f = f;
    unsigned int r = (x.v + 0x7fffu + ((x.v >> 16) & 1u)) >> 16;
    return (unsigned short)r;
}
__device__ __forceinline__ float lrelu02(float v) { return v > 0.0f ? v : 0.2f * v; }

__device__ __forceinline__ void gload16(const void* g, void* l) {
    __builtin_amdgcn_global_load_lds(
        (const __attribute__((address_space(1))) void*)g,
        (__attribute__((address_space(3))) void*)l, 16, 0, 0);
}

// ---------------------------------------------------------------------------
// bf16 MFMA GEMM, 128x128 tile, BK=32, 4 waves (2x2 of 64x64), dbuf LDS.
// (unchanged from R1 — correct and not the current bottleneck)
// ---------------------------------------------------------------------------
template<int ASRC, int EPI>
__global__ __launch_bounds__(256) void mgemm_k(
    const unsigned short* __restrict__ A0, const unsigned short* __restrict__ A1,
    const int* __restrict__ idxU, const int* __restrict__ idxV,
    const unsigned short* __restrict__ BT,
    const float* __restrict__ bias, const float* __restrict__ w2,
    unsigned short* __restrict__ Cb, float* __restrict__ outp,
    int M, int K, int Nn)
{
    __shared__ unsigned short As[2][4096];
    __shared__ unsigned short Bs[2][4096];

    const int tid = threadIdx.x;
    const int wave = tid >> 6, lane = tid & 63;
    const int row0 = blockIdx.x * 128, col0 = blockIdx.y * 128;
    const int ksub = (lane & 3) * 8;

    const unsigned short* aL[2];
    const unsigned short* aH[2];
    const unsigned short* bP[2];
    #pragma unroll
    for (int j = 0; j < 2; ++j) {
        const int r = j * 64 + wave * 16 + (lane >> 2);
        int ar = row0 + r; if (ar > M - 1) ar = M - 1;
        if (ASRC == 0)      { aL[j] = A0 + (long)ar * K;  aH[j] = aL[j]; }
        else if (ASRC == 1) { aL[j] = A0 + (long)ar * 256; aH[j] = A1 + (long)ar * 256; }
        else { const int u = idxU[ar], v = idxV[ar];
               aL[j] = A0 + (long)u * 256;  aH[j] = A0 + (long)v * 256; }
        bP[j] = BT + (long)(col0 + r) * K;
    }

    const int wm = wave >> 1, wn = wave & 1;
    const int lrow = lane & 15, lk = (lane >> 4) * 8;

    f32x4 acc[4][4] = {};

    const int nT = K >> 5;
    int buf = 0;

    auto stage = [&](int bi, int t) {
        const int k0 = t << 5;
        #pragma unroll
        for (int j = 0; j < 2; ++j) {
            const unsigned short* ga;
            if (ASRC == 0) ga = aL[j] + k0 + ksub;
            else ga = (k0 < 256) ? (aL[j] + k0 + ksub) : (aH[j] + (k0 - 256) + ksub);
            const int ci = j * 256 + wave * 64 + lane;
            gload16(ga, &As[bi][ci * 8]);
            gload16(bP[j] + k0 + ksub, &Bs[bi][ci * 8]);
        }
    };

    stage(0, 0);
    __syncthreads();
    for (int t = 0; t < nT; ++t) {
        if (t + 1 < nT) stage(buf ^ 1, t + 1);
        bf16x8 a[4], b[4];
        #pragma unroll
        for (int i = 0; i < 4; ++i)
            a[i] = *(const bf16x8*)&As[buf][(wm * 64 + i * 16 + lrow) * 32 + lk];
        #pragma unroll
        for (int j = 0; j < 4; ++j)
            b[j] = *(const bf16x8*)&Bs[buf][(wn * 64 + j * 16 + lrow) * 32 + lk];
        #pragma unroll
        for (int i = 0; i < 4; ++i)
            #pragma unroll
            for (int j = 0; j < 4; ++j)
                acc[i][j] = __builtin_amdgcn_mfma_f32_16x16x32_bf16(a[i], b[j], acc[i][j], 0, 0, 0);
        __syncthreads();
        buf ^= 1;
    }

    if constexpr (EPI == 0 || EPI == 1) {
        #pragma unroll
        for (int i = 0; i < 4; ++i) {
            #pragma unroll
            for (int p = 0; p < 4; ++p) {
                const int row = row0 + wm * 64 + i * 16 + (lane >> 4) * 4 + p;
                if (row < M) {
                    #pragma unroll
                    for (int j = 0; j < 4; ++j) {
                        const int col = col0 + wn * 64 + j * 16 + (lane & 15);
                        float v = acc[i][j][p];
                        if (EPI == 1) { v += bias[col]; v = v > 0.f ? v : 0.f; }
                        Cb[(long)row * Nn + col] = f2b(v);
                    }
                }
            }
        }
    } else {
        float s[4][4];
        #pragma unroll
        for (int i = 0; i < 4; ++i) {
            #pragma unroll
            for (int p = 0; p < 4; ++p) {
                float t = 0.f;
                #pragma unroll
                for (int j = 0; j < 4; ++j) {
                    const int col = col0 + wn * 64 + j * 16 + (lane & 15);
                    float v = acc[i][j][p] + bias[col];
                    v = v > 0.f ? v : 0.f;
                    t += v * w2[col];
                }
                s[i][p] = t;
            }
        }
        #pragma unroll
        for (int off = 1; off < 16; off <<= 1) {
            #pragma unroll
            for (int i = 0; i < 4; ++i)
                #pragma unroll
                for (int p = 0; p < 4; ++p)
                    s[i][p] += __shfl_xor(s[i][p], off);
        }
        if ((lane & 15) == 0) {
            #pragma unroll
            for (int i = 0; i < 4; ++i)
                #pragma unroll
                for (int p = 0; p < 4; ++p) {
                    const int row = row0 + wm * 64 + i * 16 + (lane >> 4) * 4 + p;
                    if (row < M) atomicAdd(outp + row, s[i][p]);
                }
        }
    }
}

// ---------------------------------------------------------------------------
// small prep kernels
// ---------------------------------------------------------------------------
__global__ __launch_bounds__(256) void castx_k(const float* __restrict__ x,
                                               unsigned short* __restrict__ xb)
{
    const int id = blockIdx.x * 256 + threadIdx.x;
    const float4 v = ((const float4*)x)[id];
    ushort4 o;
    o.x = f2b(v.x); o.y = f2b(v.y); o.z = f2b(v.z); o.w = f2b(v.w);
    ((ushort4*)xb)[id] = o;
}

__global__ __launch_bounds__(256) void tr_k(const float* __restrict__ B,
                                            unsigned short* __restrict__ BT,
                                            int K, int N)
{
    const int id = blockIdx.x * 256 + threadIdx.x;
    const int k = id / N, n = id % N;
    BT[(long)n * K + k] = f2b(B[id]);
}

// ---------------------------------------------------------------------------
// alpha kernels (bf16 h inputs)
// ---------------------------------------------------------------------------
__global__ __launch_bounds__(256) void alpha1_k(
    const unsigned short* __restrict__ h1, const float* __restrict__ a1s,
    const float* __restrict__ a1d, float* __restrict__ as1, float* __restrict__ ad1)
{
    const int wid = threadIdx.x >> 6;
    const int lane = threadIdx.x & 63;
    const int n = blockIdx.x * 4 + wid;
    if (n >= N_NODES) return;
    float ps[4], pd[4];
    #pragma unroll
    for (int h = 0; h < 4; ++h) {
        const float hv = b2f(h1[(long)n * 256 + h * 64 + lane]);
        ps[h] = hv * a1s[h * 64 + lane];
        pd[h] = hv * a1d[h * 64 + lane];
    }
    #pragma unroll
    for (int off = 32; off > 0; off >>= 1) {
        #pragma unroll
        for (int h = 0; h < 4; ++h) {
            ps[h] += __shfl_xor(ps[h], off);
            pd[h] += __shfl_xor(pd[h], off);
        }
    }
    if (lane == 0) {
        #pragma unroll
        for (int h = 0; h < 4; ++h) {
            as1[n * 4 + h] = ps[h];
            ad1[n * 4 + h] = pd[h];
        }
    }
}

__global__ __launch_bounds__(256) void alpha2_k(
    const unsigned short* __restrict__ h2, const float* __restrict__ a2s,
    const float* __restrict__ a2d, float* __restrict__ as2, float* __restrict__ ad2)
{
    const int wid = threadIdx.x >> 6;
    const int lane = threadIdx.x & 63;
    const int n = blockIdx.x * 4 + wid;
    if (n >= N_NODES) return;
    float ps = 0.f, pd = 0.f;
    #pragma unroll
    for (int q = 0; q < 4; ++q) {
        const float hv = b2f(h2[(long)n * 256 + q * 64 + lane]);
        ps += hv * a2s[q * 64 + lane];
        pd += hv * a2d[q * 64 + lane];
    }
    #pragma unroll
    for (int off = 32; off > 0; off >>= 1) {
        ps += __shfl_xor(ps, off);
        pd += __shfl_xor(pd, off);
    }
    if (lane == 0) { as2[n] = ps; ad2[n] = pd; }
}

// ---------------------------------------------------------------------------
// CSR construction (by dst, self-loops via deg init = 1)
// ---------------------------------------------------------------------------
__global__ __launch_bounds__(256) void deg_init_k(int* __restrict__ deg)
{
    const int i = blockIdx.x * 256 + threadIdx.x;
    if (i < N_NODES) deg[i] = 1;
}

__global__ __launch_bounds__(256) void deg_count_k(const int* __restrict__ ei, int* __restrict__ deg)
{
    const int e = blockIdx.x * 256 + threadIdx.x;
    if (e < N_EDGES) atomicAdd(&deg[ei[N_EDGES + e]], 1);
}

__global__ __launch_bounds__(1024) void scan_k(const int* __restrict__ deg,
                                               int* __restrict__ indptr,
                                               int* __restrict__ pos)
{
    __shared__ int sums[1024];
    const int tid = threadIdx.x;
    const int CH = 20;
    const int start = tid * CH;
    const int end = min(start + CH, N_NODES);
    int s = 0;
    for (int i = start; i < end; ++i) s += deg[i];
    sums[tid] = s;
    __syncthreads();
    for (int off = 1; off < 1024; off <<= 1) {
        const int v = sums[tid];
        const int add = (tid >= off) ? sums[tid - off] : 0;
        __syncthreads();
        sums[tid] = v + add;
        __syncthreads();
    }
    int pre = sums[tid] - s;
    for (int i = start; i < end; ++i) {
        indptr[i] = pre;
        pos[i] = pre;
        pre += deg[i];
    }
    if (tid == 1023) indptr[N_NODES] = sums[1023];
}

__global__ __launch_bounds__(256) void fill_k(const int* __restrict__ ei,
                                              int* __restrict__ pos, int* __restrict__ csr)
{
    const int i = blockIdx.x * 256 + threadIdx.x;
    if (i < N_EDGES) {
        const int s = ei[i], d = ei[N_EDGES + i];
        const int p = atomicAdd(&pos[d], 1);
        csr[p] = s;
    } else if (i < EPRIME) {
        const int n = i - N_EDGES;
        const int p = atomicAdd(&pos[n], 1);
        csr[p] = n;
    }
}

// ---------------------------------------------------------------------------
// Fused GAT aggregation conv1: ONE WAVE PER NODE, single pass.
// Softmax shift-invariance: skip max-subtraction (logits are O(3) here);
// accumulate unnormalized p*h and divide by wave-reduced sum(p) at the end.
// Lane e stages (src, p[4 heads]) in this wave's LDS slot; gather loop does
// one ushort4 (4 channels) load per edge per lane (wave = 512B/row).
// Wave-synchronous LDS: lockstep lanes + lgkmcnt(0) + sched/wave barriers.
// ---------------------------------------------------------------------------
__global__ __launch_bounds__(256) void agg1_k(
    const unsigned short* __restrict__ h1, const float* __restrict__ as1,
    const float* __restrict__ ad1, const int* __restrict__ indptr,
    const int* __restrict__ csr, const float* __restrict__ b1,
    unsigned short* __restrict__ out)
{
    __shared__ int   ssrc[4][64];
    __shared__ float sp[4][64 * 4];
    const int wv = threadIdx.x >> 6, lane = threadIdx.x & 63;
    const int n = blockIdx.x * 4 + wv;
    if (n >= N_NODES) return;

    const int beg = indptr[n], end = indptr[n + 1];
    const float4 ad = ((const float4*)ad1)[n];
    const int c0 = lane * 4;          // this lane's 4 channels
    const int hd = lane >> 4;         // head of those channels

    float acc[4] = {0.f, 0.f, 0.f, 0.f};
    float psum[4] = {0.f, 0.f, 0.f, 0.f};

    for (int base = beg; base < end; base += 64) {
        const int cnt = min(64, end - base);
        if (lane < cnt) {
            const int s = csr[base + lane];
            const float4 av = ((const float4*)as1)[s];
            float4 p;
            p.x = __expf(lrelu02(av.x + ad.x));
            p.y = __expf(lrelu02(av.y + ad.y));
            p.z = __expf(lrelu02(av.z + ad.z));
            p.w = __expf(lrelu02(av.w + ad.w));
            ssrc[wv][lane] = s;
            *(float4*)&sp[wv][lane * 4] = p;
            psum[0] += p.x; psum[1] += p.y; psum[2] += p.z; psum[3] += p.w;
        }
        asm volatile("s_waitcnt lgkmcnt(0)" ::: "memory");
        __builtin_amdgcn_sched_barrier(0);
        for (int e = 0; e < cnt; ++e) {
            const int s = ssrc[wv][e];
            const float w = sp[wv][e * 4 + hd];
            const ushort4 hv = *(const ushort4*)&h1[(long)s * 256 + c0];
            acc[0] = fmaf(w, b2f(hv.x), acc[0]);
            acc[1] = fmaf(w, b2f(hv.y), acc[1]);
            acc[2] = fmaf(w, b2f(hv.z), acc[2]);
            acc[3] = fmaf(w, b2f(hv.w), acc[3]);
        }
        __builtin_amdgcn_sched_barrier(0);
        __builtin_amdgcn_wave_barrier();
    }

    // wave-reduce psum (all heads), every lane needs its head's total
    #pragma unroll
    for (int off = 1; off < 64; off <<= 1) {
        #pragma unroll
        for (int h = 0; h < 4; ++h) psum[h] += __shfl_xor(psum[h], off);
    }
    const float invd = 1.0f / psum[hd];

    ushort4 o;
    float v;
    v = acc[0] * invd + b1[c0 + 0]; o.x = f2b(v > 0.f ? v : (__expf(v) - 1.0f));
    v = acc[1] * invd + b1[c0 + 1]; o.y = f2b(v > 0.f ? v : (__expf(v) - 1.0f));
    v = acc[2] * invd + b1[c0 + 2]; o.z = f2b(v > 0.f ? v : (__expf(v) - 1.0f));
    v = acc[3] * invd + b1[c0 + 3]; o.w = f2b(v > 0.f ? v : (__expf(v) - 1.0f));
    *(ushort4*)&out[(long)n * 256 + c0] = o;
}

// conv2: 1 head x 256 ch, +b2, bf16 in/out — same structure
__global__ __launch_bounds__(256) void agg2_k(
    const unsigned short* __restrict__ h2, const float* __restrict__ as2,
    const float* __restrict__ ad2, const int* __restrict__ indptr,
    const int* __restrict__ csr, const float* __restrict__ b2,
    unsigned short* __restrict__ outb)
{
    __shared__ int   ssrc[4][64];
    __shared__ float sp[4][64];
    const int wv = threadIdx.x >> 6, lane = threadIdx.x & 63;
    const int n = blockIdx.x * 4 + wv;
    if (n >= N_NODES) return;

    const int beg = indptr[n], end = indptr[n + 1];
    const float adv = ad2[n];
    const int c0 = lane * 4;

    float acc[4] = {0.f, 0.f, 0.f, 0.f};
    float psum = 0.f;

    for (int base = beg; base < end; base += 64) {
        const int cnt = min(64, end - base);
        if (lane < cnt) {
            const int s = csr[base + lane];
            const float p = __expf(lrelu02(as2[s] + adv));
            ssrc[wv][lane] = s;
            sp[wv][lane] = p;
            psum += p;
        }
        asm volatile("s_waitcnt lgkmcnt(0)" ::: "memory");
        __builtin_amdgcn_sched_barrier(0);
        for (int e = 0; e < cnt; ++e) {
            const int s = ssrc[wv][e];
            const float w = sp[wv][e];
            const ushort4 hv = *(const ushort4*)&h2[(long)s * 256 + c0];
            acc[0] = fmaf(w, b2f(hv.x), acc[0]);
            acc[1] = fmaf(w, b2f(hv.y), acc[1]);
            acc[2] = fmaf(w, b2f(hv.z), acc[2]);
            acc[3] = fmaf(w, b2f(hv.w), acc[3]);
        }
        __builtin_amdgcn_sched_barrier(0);
        __builtin_amdgcn_wave_barrier();
    }

    #pragma unroll
    for (int off = 1; off < 64; off <<= 1) psum += __shfl_xor(psum, off);
    const float invd = 1.0f / psum;

    ushort4 o;
    o.x = f2b(acc[0] * invd + b2[c0 + 0]);
    o.y = f2b(acc[1] * invd + b2[c0 + 1]);
    o.z = f2b(acc[2] * invd + b2[c0 + 2]);
    o.w = f2b(acc[3] * invd + b2[c0 + 3]);
    *(ushort4*)&outb[(long)n * 256 + c0] = o;
}

// ---------------------------------------------------------------------------
// gate finalize: g = sigmoid(ghid.gw2 + gb2); hf = (1-g)*x + g*hg  (bf16 out)
// ---------------------------------------------------------------------------
__global__ __launch_bounds__(256) void gatefin_k(
    const unsigned short* __restrict__ ghid, const float* __restrict__ gw2,
    const float* __restrict__ gb2, const float* __restrict__ x,
    const unsigned short* __restrict__ hgb, unsigned short* __restrict__ hfb)
{
    const int wid = threadIdx.x >> 6;
    const int lane = threadIdx.x & 63;
    const int n = blockIdx.x * 4 + wid;
    if (n >= N_NODES) return;
    float s = 0.f;
    #pragma unroll
    for (int q = 0; q < 4; ++q)
        s += b2f(ghid[(long)n * 256 + q * 64 + lane]) * gw2[q * 64 + lane];
    #pragma unroll
    for (int off = 32; off > 0; off >>= 1) s += __shfl_xor(s, off);
    const float g = 1.0f / (1.0f + __expf(-(s + gb2[0])));
    #pragma unroll
    for (int q = 0; q < 4; ++q) {
        const int c = q * 64 + lane;
        const float xv = x[(long)n * 256 + c];
        const float hv = b2f(hgb[(long)n * 256 + c]);
        hfb[(long)n * 256 + c] = f2b((1.0f - g) * xv + g * hv);
    }
}

__global__ __launch_bounds__(256) void outinit_k(float* __restrict__ out, const float* __restrict__ pb2)
{
    const int p = blockIdx.x * 256 + threadIdx.x;
    if (p < NP) out[p] = pb2[0];
}

// ---------------------------------------------------------------------------
extern "C" void kernel_launch(void* const* d_in, const int* in_sizes, int n_in,
                              void* d_out, int out_size, void* d_ws, size_t ws_size,
                              hipStream_t stream)
{
    const float* x   = (const float*)d_in[0];
    const int*   ei  = (const int*)d_in[1];
    const int*   un  = (const int*)d_in[2];
    const int*   vn  = (const int*)d_in[3];
    const float* W1  = (const float*)d_in[4];
    const float* a1s = (const float*)d_in[5];
    const float* a1d = (const float*)d_in[6];
    const float* b1  = (const float*)d_in[7];
    const float* W2  = (const float*)d_in[8];
    const float* a2s = (const float*)d_in[9];
    const float* a2d = (const float*)d_in[10];
    const float* b2  = (const float*)d_in[11];
    const float* gw1 = (const float*)d_in[12];
    const float* gb1 = (const float*)d_in[13];
    const float* gw2 = (const float*)d_in[14];
    const float* gb2 = (const float*)d_in[15];
    const float* pw1 = (const float*)d_in[16];
    const float* pb1 = (const float*)d_in[17];
    const float* pw2 = (const float*)d_in[18];
    const float* pb2 = (const float*)d_in[19];
    float* out = (float*)d_out;

    // workspace layout
    unsigned short* bufHb = (unsigned short*)d_ws;        // h1b / h2b / ghidb
    unsigned short* h1ab  = bufHb + 5120000;              // agg1 out; later hfb
    unsigned short* hgb   = h1ab + 5120000;
    unsigned short* xb    = hgb + 5120000;
    unsigned short* W1t   = xb + 5120000;
    unsigned short* W2t   = W1t + 65536;
    unsigned short* gw1t  = W2t + 65536;
    unsigned short* pw1t  = gw1t + 131072;
    float* as1v = (float*)(pw1t + 262144);
    float* ad1v = as1v + 80000;
    float* as2v = ad1v + 80000;
    float* ad2v = as2v + 20000;
    int* deg    = (int*)(ad2v + 20000);
    int* indptr = deg + 20000;
    int* pos    = indptr + 20032;
    int* csr    = pos + 20000;
    if (ws_size < 46u * 1024u * 1024u) return;

    dim3 b256(256);

    // prep: casts + weight transposes + CSR (all independent)
    castx_k<<<5000, b256, 0, stream>>>(x, xb);
    tr_k<<<65536 / 256, b256, 0, stream>>>(W1, W1t, 256, 256);
    tr_k<<<65536 / 256, b256, 0, stream>>>(W2, W2t, 256, 256);
    tr_k<<<131072 / 256, b256, 0, stream>>>(gw1, gw1t, 512, 256);
    tr_k<<<262144 / 256, b256, 0, stream>>>(pw1, pw1t, 512, 512);
    deg_init_k<<<(N_NODES + 255) / 256, b256, 0, stream>>>(deg);
    deg_count_k<<<(N_EDGES + 255) / 256, b256, 0, stream>>>(ei, deg);
    scan_k<<<1, 1024, 0, stream>>>(deg, indptr, pos);
    fill_k<<<(EPRIME + 255) / 256, b256, 0, stream>>>(ei, pos, csr);

    // conv1: h1b = xb @ W1
    mgemm_k<0, 0><<<dim3(157, 2), b256, 0, stream>>>(
        xb, nullptr, nullptr, nullptr, W1t, nullptr, nullptr, bufHb, nullptr,
        N_NODES, 256, 256);
    alpha1_k<<<5000, b256, 0, stream>>>(bufHb, a1s, a1d, as1v, ad1v);
    agg1_k<<<5000, b256, 0, stream>>>(bufHb, as1v, ad1v, indptr, csr, b1, h1ab);

    // conv2: h2b = h1a @ W2
    mgemm_k<0, 0><<<dim3(157, 2), b256, 0, stream>>>(
        h1ab, nullptr, nullptr, nullptr, W2t, nullptr, nullptr, bufHb, nullptr,
        N_NODES, 256, 256);
    alpha2_k<<<5000, b256, 0, stream>>>(bufHb, a2s, a2d, as2v, ad2v);
    agg2_k<<<5000, b256, 0, stream>>>(bufHb, as2v, ad2v, indptr, csr, b2, hgb);

    // gate MLP hidden: ghidb = relu(concat(xb,hgb) @ gw1 + gb1)
    mgemm_k<1, 1><<<dim3(157, 2), b256, 0, stream>>>(
        xb, hgb, nullptr, nullptr, gw1t, gb1, nullptr, bufHb, nullptr,
        N_NODES, 512, 256);
    gatefin_k<<<5000, b256, 0, stream>>>(bufHb, gw2, gb2, x, hgb, h1ab);

    // predictor
    outinit_k<<<(NP + 255) / 256, b256, 0, stream>>>(out, pb2);
    mgemm_k<2, 2><<<dim3(782, 4), b256, 0, stream>>>(
        h1ab, nullptr, un, vn, pw1t, pb1, pw2, nullptr, out,
        NP, 512, 512);
}

// Round 4
// 290.544 us; speedup vs baseline: 3.9308x; 1.0076x over previous
//
#include <hip/hip_runtime.h>
#include <math.h>

#define N_NODES 20000
#define N_EDGES 320000
#define EPRIME  (N_EDGES + N_NODES)
#define NP      100000

typedef __bf16 bf16x8 __attribute__((ext_vector_type(8)));
typedef float  f32x4  __attribute__((ext_vector_type(4)));

__device__ __forceinline__ float b2f(unsigned short u) {
    union { float f; unsigned int v; } x; x.v = ((unsigned int)u) << 16; return x.f;
}
__device__ __forceinline__ unsigned short f2b(float f) {
    union { float f; unsigned int v; } x; x.f = f;
    unsigned int r = (x.v + 0x7fffu + ((x.v >> 16) & 1u)) >> 16;
    return (unsigned short)r;
}
__device__ __forceinline__ float lrelu02(float v) { return v > 0.0f ? v : 0.2f * v; }

__device__ __forceinline__ void gload16(const void* g, void* l) {
    __builtin_amdgcn_global_load_lds(
        (const __attribute__((address_space(1))) void*)g,
        (__attribute__((address_space(3))) void*)l, 16, 0, 0);
}

// ---------------------------------------------------------------------------
// bf16 MFMA GEMM, 128x128 tile, BK=32, 4 waves (2x2 of 64x64), dbuf LDS.
// LDS tile [128][32] bf16 (row = 4 x 16B chunks). Bank-conflict fix (R3):
// chunk c of row r is stored at slot c ^ ((r>>1)&3). Staging keeps LDS
// linear (global_load_lds requirement) and pre-swizzles the GLOBAL source
// chunk; the fragment read applies the same XOR. Both reduce to per-lane
// constants: stage (lane&3)^((lane>>3)&3), read (lane>>4)^((lane>>1)&3).
// 16 lanes then hit eight 4-bank groups 2-way => conflict-free (m136).
// ---------------------------------------------------------------------------
template<int ASRC, int EPI>
__global__ __launch_bounds__(256) void mgemm_k(
    const unsigned short* __restrict__ A0, const unsigned short* __restrict__ A1,
    const int* __restrict__ idxU, const int* __restrict__ idxV,
    const unsigned short* __restrict__ BT,
    const float* __restrict__ bias, const float* __restrict__ w2,
    unsigned short* __restrict__ Cb, float* __restrict__ outp,
    int M, int K, int Nn)
{
    __shared__ unsigned short As[2][4096];
    __shared__ unsigned short Bs[2][4096];

    const int tid = threadIdx.x;
    const int wave = tid >> 6, lane = tid & 63;
    const int row0 = blockIdx.x * 128, col0 = blockIdx.y * 128;
    // swizzled 16B-chunk offset (bf16 elems) for the GLOBAL source of this
    // lane's staging slot: chunk = (lane&3) ^ f(row), f(row)=(row>>1)&3 and
    // row = j*64+wave*16+(lane>>2) => f = (lane>>3)&3 (j,wave only set bits>=4)
    const int ksub = (((lane & 3) ^ ((lane >> 3) & 3)) * 8);

    const unsigned short* aL[2];
    const unsigned short* aH[2];
    const unsigned short* bP[2];
    #pragma unroll
    for (int j = 0; j < 2; ++j) {
        const int r = j * 64 + wave * 16 + (lane >> 2);
        int ar = row0 + r; if (ar > M - 1) ar = M - 1;
        if (ASRC == 0)      { aL[j] = A0 + (long)ar * K;  aH[j] = aL[j]; }
        else if (ASRC == 1) { aL[j] = A0 + (long)ar * 256; aH[j] = A1 + (long)ar * 256; }
        else { const int u = idxU[ar], v = idxV[ar];
               aL[j] = A0 + (long)u * 256;  aH[j] = A0 + (long)v * 256; }
        bP[j] = BT + (long)(col0 + r) * K;
    }

    const int wm = wave >> 1, wn = wave & 1;
    const int lrow = lane & 15;
    // swizzled read chunk: want data chunk (lane>>4) of row (..+lrow);
    // slot = (lane>>4) ^ ((row>>1)&3) = (lane>>4) ^ ((lane>>1)&3)
    const int lks = ((((lane >> 4) ^ ((lane >> 1) & 3)) & 3) * 8);

    f32x4 acc[4][4] = {};

    const int nT = K >> 5;
    int buf = 0;

    auto stage = [&](int bi, int t) {
        const int k0 = t << 5;
        #pragma unroll
        for (int j = 0; j < 2; ++j) {
            const unsigned short* ga;
            if (ASRC == 0) ga = aL[j] + k0 + ksub;
            else ga = (k0 < 256) ? (aL[j] + k0 + ksub) : (aH[j] + (k0 - 256) + ksub);
            const int ci = j * 256 + wave * 64 + lane;
            gload16(ga, &As[bi][ci * 8]);
            gload16(bP[j] + k0 + ksub, &Bs[bi][ci * 8]);
        }
    };

    stage(0, 0);
    __syncthreads();
    for (int t = 0; t < nT; ++t) {
        if (t + 1 < nT) stage(buf ^ 1, t + 1);
        bf16x8 a[4], b[4];
        #pragma unroll
        for (int i = 0; i < 4; ++i)
            a[i] = *(const bf16x8*)&As[buf][(wm * 64 + i * 16 + lrow) * 32 + lks];
        #pragma unroll
        for (int j = 0; j < 4; ++j)
            b[j] = *(const bf16x8*)&Bs[buf][(wn * 64 + j * 16 + lrow) * 32 + lks];
        #pragma unroll
        for (int i = 0; i < 4; ++i)
            #pragma unroll
            for (int j = 0; j < 4; ++j)
                acc[i][j] = __builtin_amdgcn_mfma_f32_16x16x32_bf16(a[i], b[j], acc[i][j], 0, 0, 0);
        __syncthreads();
        buf ^= 1;
    }

    if constexpr (EPI == 0 || EPI == 1) {
        #pragma unroll
        for (int i = 0; i < 4; ++i) {
            #pragma unroll
            for (int p = 0; p < 4; ++p) {
                const int row = row0 + wm * 64 + i * 16 + (lane >> 4) * 4 + p;
                if (row < M) {
                    #pragma unroll
                    for (int j = 0; j < 4; ++j) {
                        const int col = col0 + wn * 64 + j * 16 + (lane & 15);
                        float v = acc[i][j][p];
                        if (EPI == 1) { v += bias[col]; v = v > 0.f ? v : 0.f; }
                        Cb[(long)row * Nn + col] = f2b(v);
                    }
                }
            }
        }
    } else {
        float s[4][4];
        #pragma unroll
        for (int i = 0; i < 4; ++i) {
            #pragma unroll
            for (int p = 0; p < 4; ++p) {
                float t = 0.f;
                #pragma unroll
                for (int j = 0; j < 4; ++j) {
                    const int col = col0 + wn * 64 + j * 16 + (lane & 15);
                    float v = acc[i][j][p] + bias[col];
                    v = v > 0.f ? v : 0.f;
                    t += v * w2[col];
                }
                s[i][p] = t;
            }
        }
        #pragma unroll
        for (int off = 1; off < 16; off <<= 1) {
            #pragma unroll
            for (int i = 0; i < 4; ++i)
                #pragma unroll
                for (int p = 0; p < 4; ++p)
                    s[i][p] += __shfl_xor(s[i][p], off);
        }
        if ((lane & 15) == 0) {
            #pragma unroll
            for (int i = 0; i < 4; ++i)
                #pragma unroll
                for (int p = 0; p < 4; ++p) {
                    const int row = row0 + wm * 64 + i * 16 + (lane >> 4) * 4 + p;
                    if (row < M) atomicAdd(outp + row, s[i][p]);
                }
        }
    }
}

// ---------------------------------------------------------------------------
// small prep kernels
// ---------------------------------------------------------------------------
__global__ __launch_bounds__(256) void castx_k(const float* __restrict__ x,
                                               unsigned short* __restrict__ xb)
{
    const int id = blockIdx.x * 256 + threadIdx.x;
    const float4 v = ((const float4*)x)[id];
    ushort4 o;
    o.x = f2b(v.x); o.y = f2b(v.y); o.z = f2b(v.z); o.w = f2b(v.w);
    ((ushort4*)xb)[id] = o;
}

__global__ __launch_bounds__(256) void tr_k(const float* __restrict__ B,
                                            unsigned short* __restrict__ BT,
                                            int K, int N)
{
    const int id = blockIdx.x * 256 + threadIdx.x;
    const int k = id / N, n = id % N;
    BT[(long)n * K + k] = f2b(B[id]);
}

// ---------------------------------------------------------------------------
// alpha kernels (bf16 h inputs)
// ---------------------------------------------------------------------------
__global__ __launch_bounds__(256) void alpha1_k(
    const unsigned short* __restrict__ h1, const float* __restrict__ a1s,
    const float* __restrict__ a1d, float* __restrict__ as1, float* __restrict__ ad1)
{
    const int wid = threadIdx.x >> 6;
    const int lane = threadIdx.x & 63;
    const int n = blockIdx.x * 4 + wid;
    if (n >= N_NODES) return;
    float ps[4], pd[4];
    #pragma unroll
    for (int h = 0; h < 4; ++h) {
        const float hv = b2f(h1[(long)n * 256 + h * 64 + lane]);
        ps[h] = hv * a1s[h * 64 + lane];
        pd[h] = hv * a1d[h * 64 + lane];
    }
    #pragma unroll
    for (int off = 32; off > 0; off >>= 1) {
        #pragma unroll
        for (int h = 0; h < 4; ++h) {
            ps[h] += __shfl_xor(ps[h], off);
            pd[h] += __shfl_xor(pd[h], off);
        }
    }
    if (lane == 0) {
        #pragma unroll
        for (int h = 0; h < 4; ++h) {
            as1[n * 4 + h] = ps[h];
            ad1[n * 4 + h] = pd[h];
        }
    }
}

__global__ __launch_bounds__(256) void alpha2_k(
    const unsigned short* __restrict__ h2, const float* __restrict__ a2s,
    const float* __restrict__ a2d, float* __restrict__ as2, float* __restrict__ ad2)
{
    const int wid = threadIdx.x >> 6;
    const int lane = threadIdx.x & 63;
    const int n = blockIdx.x * 4 + wid;
    if (n >= N_NODES) return;
    float ps = 0.f, pd = 0.f;
    #pragma unroll
    for (int q = 0; q < 4; ++q) {
        const float hv = b2f(h2[(long)n * 256 + q * 64 + lane]);
        ps += hv * a2s[q * 64 + lane];
        pd += hv * a2d[q * 64 + lane];
    }
    #pragma unroll
    for (int off = 32; off > 0; off >>= 1) {
        ps += __shfl_xor(ps, off);
        pd += __shfl_xor(pd, off);
    }
    if (lane == 0) { as2[n] = ps; ad2[n] = pd; }
}

// ---------------------------------------------------------------------------
// CSR construction (by dst, self-loops via deg init = 1)
// ---------------------------------------------------------------------------
__global__ __launch_bounds__(256) void deg_init_k(int* __restrict__ deg)
{
    const int i = blockIdx.x * 256 + threadIdx.x;
    if (i < N_NODES) deg[i] = 1;
}

__global__ __launch_bounds__(256) void deg_count_k(const int* __restrict__ ei, int* __restrict__ deg)
{
    const int e = blockIdx.x * 256 + threadIdx.x;
    if (e < N_EDGES) atomicAdd(&deg[ei[N_EDGES + e]], 1);
}

__global__ __launch_bounds__(1024) void scan_k(const int* __restrict__ deg,
                                               int* __restrict__ indptr,
                                               int* __restrict__ pos)
{
    __shared__ int sums[1024];
    const int tid = threadIdx.x;
    const int CH = 20;
    const int start = tid * CH;
    const int end = min(start + CH, N_NODES);
    int s = 0;
    for (int i = start; i < end; ++i) s += deg[i];
    sums[tid] = s;
    __syncthreads();
    for (int off = 1; off < 1024; off <<= 1) {
        const int v = sums[tid];
        const int add = (tid >= off) ? sums[tid - off] : 0;
        __syncthreads();
        sums[tid] = v + add;
        __syncthreads();
    }
    int pre = sums[tid] - s;
    for (int i = start; i < end; ++i) {
        indptr[i] = pre;
        pos[i] = pre;
        pre += deg[i];
    }
    if (tid == 1023) indptr[N_NODES] = sums[1023];
}

__global__ __launch_bounds__(256) void fill_k(const int* __restrict__ ei,
                                              int* __restrict__ pos, int* __restrict__ csr)
{
    const int i = blockIdx.x * 256 + threadIdx.x;
    if (i < N_EDGES) {
        const int s = ei[i], d = ei[N_EDGES + i];
        const int p = atomicAdd(&pos[d], 1);
        csr[p] = s;
    } else if (i < EPRIME) {
        const int n = i - N_EDGES;
        const int p = atomicAdd(&pos[n], 1);
        csr[p] = n;
    }
}

// ---------------------------------------------------------------------------
// Fused GAT aggregation conv1: one wave per node, single pass (R2 version).
// ---------------------------------------------------------------------------
__global__ __launch_bounds__(256) void agg1_k(
    const unsigned short* __restrict__ h1, const float* __restrict__ as1,
    const float* __restrict__ ad1, const int* __restrict__ indptr,
    const int* __restrict__ csr, const float* __restrict__ b1,
    unsigned short* __restrict__ out)
{
    __shared__ int   ssrc[4][64];
    __shared__ float sp[4][64 * 4];
    const int wv = threadIdx.x >> 6, lane = threadIdx.x & 63;
    const int n = blockIdx.x * 4 + wv;
    if (n >= N_NODES) return;

    const int beg = indptr[n], end = indptr[n + 1];
    const float4 ad = ((const float4*)ad1)[n];
    const int c0 = lane * 4;
    const int hd = lane >> 4;

    float acc[4] = {0.f, 0.f, 0.f, 0.f};
    float psum[4] = {0.f, 0.f, 0.f, 0.f};

    for (int base = beg; base < end; base += 64) {
        const int cnt = min(64, end - base);
        if (lane < cnt) {
            const int s = csr[base + lane];
            const float4 av = ((const float4*)as1)[s];
            float4 p;
            p.x = __expf(lrelu02(av.x + ad.x));
            p.y = __expf(lrelu02(av.y + ad.y));
            p.z = __expf(lrelu02(av.z + ad.z));
            p.w = __expf(lrelu02(av.w + ad.w));
            ssrc[wv][lane] = s;
            *(float4*)&sp[wv][lane * 4] = p;
            psum[0] += p.x; psum[1] += p.y; psum[2] += p.z; psum[3] += p.w;
        }
        asm volatile("s_waitcnt lgkmcnt(0)" ::: "memory");
        __builtin_amdgcn_sched_barrier(0);
        for (int e = 0; e < cnt; ++e) {
            const int s = ssrc[wv][e];
            const float w = sp[wv][e * 4 + hd];
            const ushort4 hv = *(const ushort4*)&h1[(long)s * 256 + c0];
            acc[0] = fmaf(w, b2f(hv.x), acc[0]);
            acc[1] = fmaf(w, b2f(hv.y), acc[1]);
            acc[2] = fmaf(w, b2f(hv.z), acc[2]);
            acc[3] = fmaf(w, b2f(hv.w), acc[3]);
        }
        __builtin_amdgcn_sched_barrier(0);
        __builtin_amdgcn_wave_barrier();
    }

    #pragma unroll
    for (int off = 1; off < 64; off <<= 1) {
        #pragma unroll
        for (int h = 0; h < 4; ++h) psum[h] += __shfl_xor(psum[h], off);
    }
    const float invd = 1.0f / psum[hd];

    ushort4 o;
    float v;
    v = acc[0] * invd + b1[c0 + 0]; o.x = f2b(v > 0.f ? v : (__expf(v) - 1.0f));
    v = acc[1] * invd + b1[c0 + 1]; o.y = f2b(v > 0.f ? v : (__expf(v) - 1.0f));
    v = acc[2] * invd + b1[c0 + 2]; o.z = f2b(v > 0.f ? v : (__expf(v) - 1.0f));
    v = acc[3] * invd + b1[c0 + 3]; o.w = f2b(v > 0.f ? v : (__expf(v) - 1.0f));
    *(ushort4*)&out[(long)n * 256 + c0] = o;
}

// conv2: 1 head x 256 ch, +b2, bf16 in/out — same structure
__global__ __launch_bounds__(256) void agg2_k(
    const unsigned short* __restrict__ h2, const float* __restrict__ as2,
    const float* __restrict__ ad2, const int* __restrict__ indptr,
    const int* __restrict__ csr, const float* __restrict__ b2,
    unsigned short* __restrict__ outb)
{
    __shared__ int   ssrc[4][64];
    __shared__ float sp[4][64];
    const int wv = threadIdx.x >> 6, lane = threadIdx.x & 63;
    const int n = blockIdx.x * 4 + wv;
    if (n >= N_NODES) return;

    const int beg = indptr[n], end = indptr[n + 1];
    const float adv = ad2[n];
    const int c0 = lane * 4;

    float acc[4] = {0.f, 0.f, 0.f, 0.f};
    float psum = 0.f;

    for (int base = beg; base < end; base += 64) {
        const int cnt = min(64, end - base);
        if (lane < cnt) {
            const int s = csr[base + lane];
            const float p = __expf(lrelu02(as2[s] + adv));
            ssrc[wv][lane] = s;
            sp[wv][lane] = p;
            psum += p;
        }
        asm volatile("s_waitcnt lgkmcnt(0)" ::: "memory");
        __builtin_amdgcn_sched_barrier(0);
        for (int e = 0; e < cnt; ++e) {
            const int s = ssrc[wv][e];
            const float w = sp[wv][e];
            const ushort4 hv = *(const ushort4*)&h2[(long)s * 256 + c0];
            acc[0] = fmaf(w, b2f(hv.x), acc[0]);
            acc[1] = fmaf(w, b2f(hv.y), acc[1]);
            acc[2] = fmaf(w, b2f(hv.z), acc[2]);
            acc[3] = fmaf(w, b2f(hv.w), acc[3]);
        }
        __builtin_amdgcn_sched_barrier(0);
        __builtin_amdgcn_wave_barrier();
    }

    #pragma unroll
    for (int off = 1; off < 64; off <<= 1) psum += __shfl_xor(psum, off);
    const float invd = 1.0f / psum;

    ushort4 o;
    o.x = f2b(acc[0] * invd + b2[c0 + 0]);
    o.y = f2b(acc[1] * invd + b2[c0 + 1]);
    o.z = f2b(acc[2] * invd + b2[c0 + 2]);
    o.w = f2b(acc[3] * invd + b2[c0 + 3]);
    *(ushort4*)&outb[(long)n * 256 + c0] = o;
}

// ---------------------------------------------------------------------------
// gate finalize: g = sigmoid(ghid.gw2 + gb2); hf = (1-g)*x + g*hg  (bf16 out)
// ---------------------------------------------------------------------------
__global__ __launch_bounds__(256) void gatefin_k(
    const unsigned short* __restrict__ ghid, const float* __restrict__ gw2,
    const float* __restrict__ gb2, const float* __restrict__ x,
    const unsigned short* __restrict__ hgb, unsigned short* __restrict__ hfb)
{
    const int wid = threadIdx.x >> 6;
    const int lane = threadIdx.x & 63;
    const int n = blockIdx.x * 4 + wid;
    if (n >= N_NODES) return;
    float s = 0.f;
    #pragma unroll
    for (int q = 0; q < 4; ++q)
        s += b2f(ghid[(long)n * 256 + q * 64 + lane]) * gw2[q * 64 + lane];
    #pragma unroll
    for (int off = 32; off > 0; off >>= 1) s += __shfl_xor(s, off);
    const float g = 1.0f / (1.0f + __expf(-(s + gb2[0])));
    #pragma unroll
    for (int q = 0; q < 4; ++q) {
        const int c = q * 64 + lane;
        const float xv = x[(long)n * 256 + c];
        const float hv = b2f(hgb[(long)n * 256 + c]);
        hfb[(long)n * 256 + c] = f2b((1.0f - g) * xv + g * hv);
    }
}

__global__ __launch_bounds__(256) void outinit_k(float* __restrict__ out, const float* __restrict__ pb2)
{
    const int p = blockIdx.x * 256 + threadIdx.x;
    if (p < NP) out[p] = pb2[0];
}

// ---------------------------------------------------------------------------
extern "C" void kernel_launch(void* const* d_in, const int* in_sizes, int n_in,
                              void* d_out, int out_size, void* d_ws, size_t ws_size,
                              hipStream_t stream)
{
    const float* x   = (const float*)d_in[0];
    const int*   ei  = (const int*)d_in[1];
    const int*   un  = (const int*)d_in[2];
    const int*   vn  = (const int*)d_in[3];
    const float* W1  = (const float*)d_in[4];
    const float* a1s = (const float*)d_in[5];
    const float* a1d = (const float*)d_in[6];
    const float* b1  = (const float*)d_in[7];
    const float* W2  = (const float*)d_in[8];
    const float* a2s = (const float*)d_in[9];
    const float* a2d = (const float*)d_in[10];
    const float* b2  = (const float*)d_in[11];
    const float* gw1 = (const float*)d_in[12];
    const float* gb1 = (const float*)d_in[13];
    const float* gw2 = (const float*)d_in[14];
    const float* gb2 = (const float*)d_in[15];
    const float* pw1 = (const float*)d_in[16];
    const float* pb1 = (const float*)d_in[17];
    const float* pw2 = (const float*)d_in[18];
    const float* pb2 = (const float*)d_in[19];
    float* out = (float*)d_out;

    // workspace layout
    unsigned short* bufHb = (unsigned short*)d_ws;        // h1b / h2b / ghidb
    unsigned short* h1ab  = bufHb + 5120000;              // agg1 out; later hfb
    unsigned short* hgb   = h1ab + 5120000;
    unsigned short* xb    = hgb + 5120000;
    unsigned short* W1t   = xb + 5120000;
    unsigned short* W2t   = W1t + 65536;
    unsigned short* gw1t  = W2t + 65536;
    unsigned short* pw1t  = gw1t + 131072;
    float* as1v = (float*)(pw1t + 262144);
    float* ad1v = as1v + 80000;
    float* as2v = ad1v + 80000;
    float* ad2v = as2v + 20000;
    int* deg    = (int*)(ad2v + 20000);
    int* indptr = deg + 20000;
    int* pos    = indptr + 20032;
    int* csr    = pos + 20000;
    if (ws_size < 46u * 1024u * 1024u) return;

    dim3 b256(256);

    // prep: casts + weight transposes + CSR (all independent)
    castx_k<<<5000, b256, 0, stream>>>(x, xb);
    tr_k<<<65536 / 256, b256, 0, stream>>>(W1, W1t, 256, 256);
    tr_k<<<65536 / 256, b256, 0, stream>>>(W2, W2t, 256, 256);
    tr_k<<<131072 / 256, b256, 0, stream>>>(gw1, gw1t, 512, 256);
    tr_k<<<262144 / 256, b256, 0, stream>>>(pw1, pw1t, 512, 512);
    deg_init_k<<<(N_NODES + 255) / 256, b256, 0, stream>>>(deg);
    deg_count_k<<<(N_EDGES + 255) / 256, b256, 0, stream>>>(ei, deg);
    scan_k<<<1, 1024, 0, stream>>>(deg, indptr, pos);
    fill_k<<<(EPRIME + 255) / 256, b256, 0, stream>>>(ei, pos, csr);

    // conv1: h1b = xb @ W1
    mgemm_k<0, 0><<<dim3(157, 2), b256, 0, stream>>>(
        xb, nullptr, nullptr, nullptr, W1t, nullptr, nullptr, bufHb, nullptr,
        N_NODES, 256, 256);
    alpha1_k<<<5000, b256, 0, stream>>>(bufHb, a1s, a1d, as1v, ad1v);
    agg1_k<<<5000, b256, 0, stream>>>(bufHb, as1v, ad1v, indptr, csr, b1, h1ab);

    // conv2: h2b = h1a @ W2
    mgemm_k<0, 0><<<dim3(157, 2), b256, 0, stream>>>(
        h1ab, nullptr, nullptr, nullptr, W2t, nullptr, nullptr, bufHb, nullptr,
        N_NODES, 256, 256);
    alpha2_k<<<5000, b256, 0, stream>>>(bufHb, a2s, a2d, as2v, ad2v);
    agg2_k<<<5000, b256, 0, stream>>>(bufHb, as2v, ad2v, indptr, csr, b2, hgb);

    // gate MLP hidden: ghidb = relu(concat(xb,hgb) @ gw1 + gb1)
    mgemm_k<1, 1><<<dim3(157, 2), b256, 0, stream>>>(
        xb, hgb, nullptr, nullptr, gw1t, gb1, nullptr, bufHb, nullptr,
        N_NODES, 512, 256);
    gatefin_k<<<5000, b256, 0, stream>>>(bufHb, gw2, gb2, x, hgb, h1ab);

    // predictor
    outinit_k<<<(NP + 255) / 256, b256, 0, stream>>>(out, pb2);
    mgemm_k<2, 2><<<dim3(782, 4), b256, 0, stream>>>(
        h1ab, nullptr, un, vn, pw1t, pb1, pw2, nullptr, out,
        NP, 512, 512);
}

// Round 5
// 264.120 us; speedup vs baseline: 4.3241x; 1.1000x over previous
//
#include <hip/hip_runtime.h>
#include <math.h>

#define N_NODES 20000
#define N_EDGES 320000
#define EPRIME  (N_EDGES + N_NODES)
#define NP      100000

typedef __bf16 bf16x8 __attribute__((ext_vector_type(8)));
typedef float  f32x4  __attribute__((ext_vector_type(4)));

__device__ __forceinline__ float b2f(unsigned short u) {
    union { float f; unsigned int v; } x; x.v = ((unsigned int)u) << 16; return x.f;
}
__device__ __forceinline__ unsigned short f2b(float f) {
    union { float f; unsigned int v; } x; x.f = f;
    unsigned int r = (x.v + 0x7fffu + ((x.v >> 16) & 1u)) >> 16;
    return (unsigned short)r;
}
__device__ __forceinline__ float lrelu02(float v) { return v > 0.0f ? v : 0.2f * v; }

__device__ __forceinline__ void gload16(const void* g, void* l) {
    __builtin_amdgcn_global_load_lds(
        (const __attribute__((address_space(1))) void*)g,
        (__attribute__((address_space(3))) void*)l, 16, 0, 0);
}

// ---------------------------------------------------------------------------
// bf16 MFMA GEMM, 128x128 tile, BK=32, 4 waves (2x2 of 64x64), dbuf LDS,
// XOR-swizzled LDS chunks (R3) — conflict-free, verified by counter.
// ---------------------------------------------------------------------------
template<int ASRC, int EPI>
__global__ __launch_bounds__(256) void mgemm_k(
    const unsigned short* __restrict__ A0, const unsigned short* __restrict__ A1,
    const int* __restrict__ idxU, const int* __restrict__ idxV,
    const unsigned short* __restrict__ BT,
    const float* __restrict__ bias, const float* __restrict__ w2,
    unsigned short* __restrict__ Cb, float* __restrict__ outp,
    int M, int K, int Nn)
{
    __shared__ unsigned short As[2][4096];
    __shared__ unsigned short Bs[2][4096];

    const int tid = threadIdx.x;
    const int wave = tid >> 6, lane = tid & 63;
    const int row0 = blockIdx.x * 128, col0 = blockIdx.y * 128;
    const int ksub = (((lane & 3) ^ ((lane >> 3) & 3)) * 8);

    const unsigned short* aL[2];
    const unsigned short* aH[2];
    const unsigned short* bP[2];
    #pragma unroll
    for (int j = 0; j < 2; ++j) {
        const int r = j * 64 + wave * 16 + (lane >> 2);
        int ar = row0 + r; if (ar > M - 1) ar = M - 1;
        if (ASRC == 0)      { aL[j] = A0 + (long)ar * K;  aH[j] = aL[j]; }
        else if (ASRC == 1) { aL[j] = A0 + (long)ar * 256; aH[j] = A1 + (long)ar * 256; }
        else { const int u = idxU[ar], v = idxV[ar];
               aL[j] = A0 + (long)u * 256;  aH[j] = A0 + (long)v * 256; }
        bP[j] = BT + (long)(col0 + r) * K;
    }

    const int wm = wave >> 1, wn = wave & 1;
    const int lrow = lane & 15;
    const int lks = ((((lane >> 4) ^ ((lane >> 1) & 3)) & 3) * 8);

    f32x4 acc[4][4] = {};

    const int nT = K >> 5;
    int buf = 0;

    auto stage = [&](int bi, int t) {
        const int k0 = t << 5;
        #pragma unroll
        for (int j = 0; j < 2; ++j) {
            const unsigned short* ga;
            if (ASRC == 0) ga = aL[j] + k0 + ksub;
            else ga = (k0 < 256) ? (aL[j] + k0 + ksub) : (aH[j] + (k0 - 256) + ksub);
            const int ci = j * 256 + wave * 64 + lane;
            gload16(ga, &As[bi][ci * 8]);
            gload16(bP[j] + k0 + ksub, &Bs[bi][ci * 8]);
        }
    };

    stage(0, 0);
    __syncthreads();
    for (int t = 0; t < nT; ++t) {
        if (t + 1 < nT) stage(buf ^ 1, t + 1);
        bf16x8 a[4], b[4];
        #pragma unroll
        for (int i = 0; i < 4; ++i)
            a[i] = *(const bf16x8*)&As[buf][(wm * 64 + i * 16 + lrow) * 32 + lks];
        #pragma unroll
        for (int j = 0; j < 4; ++j)
            b[j] = *(const bf16x8*)&Bs[buf][(wn * 64 + j * 16 + lrow) * 32 + lks];
        #pragma unroll
        for (int i = 0; i < 4; ++i)
            #pragma unroll
            for (int j = 0; j < 4; ++j)
                acc[i][j] = __builtin_amdgcn_mfma_f32_16x16x32_bf16(a[i], b[j], acc[i][j], 0, 0, 0);
        __syncthreads();
        buf ^= 1;
    }

    if constexpr (EPI == 0 || EPI == 1) {
        #pragma unroll
        for (int i = 0; i < 4; ++i) {
            #pragma unroll
            for (int p = 0; p < 4; ++p) {
                const int row = row0 + wm * 64 + i * 16 + (lane >> 4) * 4 + p;
                if (row < M) {
                    #pragma unroll
                    for (int j = 0; j < 4; ++j) {
                        const int col = col0 + wn * 64 + j * 16 + (lane & 15);
                        float v = acc[i][j][p];
                        if (EPI == 1) { v += bias[col]; v = v > 0.f ? v : 0.f; }
                        Cb[(long)row * Nn + col] = f2b(v);
                    }
                }
            }
        }
    } else {
        float s[4][4];
        #pragma unroll
        for (int i = 0; i < 4; ++i) {
            #pragma unroll
            for (int p = 0; p < 4; ++p) {
                float t = 0.f;
                #pragma unroll
                for (int j = 0; j < 4; ++j) {
                    const int col = col0 + wn * 64 + j * 16 + (lane & 15);
                    float v = acc[i][j][p] + bias[col];
                    v = v > 0.f ? v : 0.f;
                    t += v * w2[col];
                }
                s[i][p] = t;
            }
        }
        #pragma unroll
        for (int off = 1; off < 16; off <<= 1) {
            #pragma unroll
            for (int i = 0; i < 4; ++i)
                #pragma unroll
                for (int p = 0; p < 4; ++p)
                    s[i][p] += __shfl_xor(s[i][p], off);
        }
        if ((lane & 15) == 0) {
            #pragma unroll
            for (int i = 0; i < 4; ++i)
                #pragma unroll
                for (int p = 0; p < 4; ++p) {
                    const int row = row0 + wm * 64 + i * 16 + (lane >> 4) * 4 + p;
                    if (row < M) atomicAdd(outp + row, s[i][p]);
                }
        }
    }
}

// ---------------------------------------------------------------------------
// pair combine: out[p] = relu(Zt[u] + Zb[v] + pb1) . pw2 + pb2
// Z layout [N_NODES][1024] bf16: cols 0..511 = Zt, 512..1023 = Zb.
// One wave per pair; lane covers 8 channels (16B load per row).
// ---------------------------------------------------------------------------
__global__ __launch_bounds__(256) void pair_k(
    const unsigned short* __restrict__ Z, const int* __restrict__ un,
    const int* __restrict__ vn, const float* __restrict__ pb1,
    const float* __restrict__ pw2, const float* __restrict__ pb2,
    float* __restrict__ out)
{
    const int wv = threadIdx.x >> 6, lane = threadIdx.x & 63;
    const int p = blockIdx.x * 4 + wv;
    if (p >= NP) return;
    const int u = un[p], v = vn[p];
    const int c0 = lane * 8;
    const uint4 zu = *(const uint4*)&Z[(long)u * 1024 + c0];
    const uint4 zv = *(const uint4*)&Z[(long)v * 1024 + 512 + c0];
    const float4 b1a = *(const float4*)&pb1[c0];
    const float4 b1b = *(const float4*)&pb1[c0 + 4];
    const float4 w2a = *(const float4*)&pw2[c0];
    const float4 w2b = *(const float4*)&pw2[c0 + 4];

    float zt[8], zb[8];
    zt[0] = b2f(zu.x & 0xffff); zt[1] = b2f(zu.x >> 16);
    zt[2] = b2f(zu.y & 0xffff); zt[3] = b2f(zu.y >> 16);
    zt[4] = b2f(zu.z & 0xffff); zt[5] = b2f(zu.z >> 16);
    zt[6] = b2f(zu.w & 0xffff); zt[7] = b2f(zu.w >> 16);
    zb[0] = b2f(zv.x & 0xffff); zb[1] = b2f(zv.x >> 16);
    zb[2] = b2f(zv.y & 0xffff); zb[3] = b2f(zv.y >> 16);
    zb[4] = b2f(zv.z & 0xffff); zb[5] = b2f(zv.z >> 16);
    zb[6] = b2f(zv.w & 0xffff); zb[7] = b2f(zv.w >> 16);

    const float bb[8] = {b1a.x, b1a.y, b1a.z, b1a.w, b1b.x, b1b.y, b1b.z, b1b.w};
    const float ww[8] = {w2a.x, w2a.y, w2a.z, w2a.w, w2b.x, w2b.y, w2b.z, w2b.w};
    float s = 0.f;
    #pragma unroll
    for (int q = 0; q < 8; ++q) {
        float t = zt[q] + zb[q] + bb[q];
        t = t > 0.f ? t : 0.f;
        s = fmaf(t, ww[q], s);
    }
    #pragma unroll
    for (int off = 1; off < 64; off <<= 1) s += __shfl_xor(s, off);
    if (lane == 0) out[p] = s + pb2[0];
}

// ---------------------------------------------------------------------------
// small prep kernels
// ---------------------------------------------------------------------------
__global__ __launch_bounds__(256) void castx_k(const float* __restrict__ x,
                                               unsigned short* __restrict__ xb)
{
    const int id = blockIdx.x * 256 + threadIdx.x;
    const float4 v = ((const float4*)x)[id];
    ushort4 o;
    o.x = f2b(v.x); o.y = f2b(v.y); o.z = f2b(v.z); o.w = f2b(v.w);
    ((ushort4*)xb)[id] = o;
}

__global__ __launch_bounds__(256) void tr_k(const float* __restrict__ B,
                                            unsigned short* __restrict__ BT,
                                            int K, int N)
{
    const int id = blockIdx.x * 256 + threadIdx.x;
    const int k = id / N, n = id % N;
    BT[(long)n * K + k] = f2b(B[id]);
}

// Z-weight transpose: BT2[j][k] (j<512: pw1[k][j]; j>=512: pw1[256+k][j-512])
// iterate source: r=id/512 row of pw1, c=id%512 col.
__global__ __launch_bounds__(256) void tr2_k(const float* __restrict__ pw1,
                                             unsigned short* __restrict__ BT2)
{
    const int id = blockIdx.x * 256 + threadIdx.x;   // 512*512
    const int r = id >> 9, c = id & 511;
    const int j = (r < 256) ? c : (512 + c);
    const int k = (r < 256) ? r : (r - 256);
    BT2[j * 256 + k] = f2b(pw1[id]);
}

// ---------------------------------------------------------------------------
// alpha kernels (bf16 h inputs)
// ---------------------------------------------------------------------------
__global__ __launch_bounds__(256) void alpha1_k(
    const unsigned short* __restrict__ h1, const float* __restrict__ a1s,
    const float* __restrict__ a1d, float* __restrict__ as1, float* __restrict__ ad1)
{
    const int wid = threadIdx.x >> 6;
    const int lane = threadIdx.x & 63;
    const int n = blockIdx.x * 4 + wid;
    if (n >= N_NODES) return;
    float ps[4], pd[4];
    #pragma unroll
    for (int h = 0; h < 4; ++h) {
        const float hv = b2f(h1[(long)n * 256 + h * 64 + lane]);
        ps[h] = hv * a1s[h * 64 + lane];
        pd[h] = hv * a1d[h * 64 + lane];
    }
    #pragma unroll
    for (int off = 32; off > 0; off >>= 1) {
        #pragma unroll
        for (int h = 0; h < 4; ++h) {
            ps[h] += __shfl_xor(ps[h], off);
            pd[h] += __shfl_xor(pd[h], off);
        }
    }
    if (lane == 0) {
        #pragma unroll
        for (int h = 0; h < 4; ++h) {
            as1[n * 4 + h] = ps[h];
            ad1[n * 4 + h] = pd[h];
        }
    }
}

__global__ __launch_bounds__(256) void alpha2_k(
    const unsigned short* __restrict__ h2, const float* __restrict__ a2s,
    const float* __restrict__ a2d, float* __restrict__ as2, float* __restrict__ ad2)
{
    const int wid = threadIdx.x >> 6;
    const int lane = threadIdx.x & 63;
    const int n = blockIdx.x * 4 + wid;
    if (n >= N_NODES) return;
    float ps = 0.f, pd = 0.f;
    #pragma unroll
    for (int q = 0; q < 4; ++q) {
        const float hv = b2f(h2[(long)n * 256 + q * 64 + lane]);
        ps += hv * a2s[q * 64 + lane];
        pd += hv * a2d[q * 64 + lane];
    }
    #pragma unroll
    for (int off = 32; off > 0; off >>= 1) {
        ps += __shfl_xor(ps, off);
        pd += __shfl_xor(pd, off);
    }
    if (lane == 0) { as2[n] = ps; ad2[n] = pd; }
}

// ---------------------------------------------------------------------------
// CSR construction (by dst, self-loops via deg init = 1)
// ---------------------------------------------------------------------------
__global__ __launch_bounds__(256) void deg_init_k(int* __restrict__ deg)
{
    const int i = blockIdx.x * 256 + threadIdx.x;
    if (i < N_NODES) deg[i] = 1;
}

__global__ __launch_bounds__(256) void deg_count_k(const int* __restrict__ ei, int* __restrict__ deg)
{
    const int e = blockIdx.x * 256 + threadIdx.x;
    if (e < N_EDGES) atomicAdd(&deg[ei[N_EDGES + e]], 1);
}

__global__ __launch_bounds__(1024) void scan_k(const int* __restrict__ deg,
                                               int* __restrict__ indptr,
                                               int* __restrict__ pos)
{
    __shared__ int sums[1024];
    const int tid = threadIdx.x;
    const int CH = 20;
    const int start = tid * CH;
    const int end = min(start + CH, N_NODES);
    int s = 0;
    for (int i = start; i < end; ++i) s += deg[i];
    sums[tid] = s;
    __syncthreads();
    for (int off = 1; off < 1024; off <<= 1) {
        const int v = sums[tid];
        const int add = (tid >= off) ? sums[tid - off] : 0;
        __syncthreads();
        sums[tid] = v + add;
        __syncthreads();
    }
    int pre = sums[tid] - s;
    for (int i = start; i < end; ++i) {
        indptr[i] = pre;
        pos[i] = pre;
        pre += deg[i];
    }
    if (tid == 1023) indptr[N_NODES] = sums[1023];
}

__global__ __launch_bounds__(256) void fill_k(const int* __restrict__ ei,
                                              int* __restrict__ pos, int* __restrict__ csr)
{
    const int i = blockIdx.x * 256 + threadIdx.x;
    if (i < N_EDGES) {
        const int s = ei[i], d = ei[N_EDGES + i];
        const int p = atomicAdd(&pos[d], 1);
        csr[p] = s;
    } else if (i < EPRIME) {
        const int n = i - N_EDGES;
        const int p = atomicAdd(&pos[n], 1);
        csr[p] = n;
    }
}

// ---------------------------------------------------------------------------
// Fused GAT aggregation conv1: one wave per node, single pass.
// ---------------------------------------------------------------------------
__global__ __launch_bounds__(256) void agg1_k(
    const unsigned short* __restrict__ h1, const float* __restrict__ as1,
    const float* __restrict__ ad1, const int* __restrict__ indptr,
    const int* __restrict__ csr, const float* __restrict__ b1,
    unsigned short* __restrict__ out)
{
    __shared__ int   ssrc[4][64];
    __shared__ float sp[4][64 * 4];
    const int wv = threadIdx.x >> 6, lane = threadIdx.x & 63;
    const int n = blockIdx.x * 4 + wv;
    if (n >= N_NODES) return;

    const int beg = indptr[n], end = indptr[n + 1];
    const float4 ad = ((const float4*)ad1)[n];
    const int c0 = lane * 4;
    const int hd = lane >> 4;

    float acc[4] = {0.f, 0.f, 0.f, 0.f};
    float psum[4] = {0.f, 0.f, 0.f, 0.f};

    for (int base = beg; base < end; base += 64) {
        const int cnt = min(64, end - base);
        if (lane < cnt) {
            const int s = csr[base + lane];
            const float4 av = ((const float4*)as1)[s];
            float4 p;
            p.x = __expf(lrelu02(av.x + ad.x));
            p.y = __expf(lrelu02(av.y + ad.y));
            p.z = __expf(lrelu02(av.z + ad.z));
            p.w = __expf(lrelu02(av.w + ad.w));
            ssrc[wv][lane] = s;
            *(float4*)&sp[wv][lane * 4] = p;
            psum[0] += p.x; psum[1] += p.y; psum[2] += p.z; psum[3] += p.w;
        }
        asm volatile("s_waitcnt lgkmcnt(0)" ::: "memory");
        __builtin_amdgcn_sched_barrier(0);
        for (int e = 0; e < cnt; ++e) {
            const int s = ssrc[wv][e];
            const float w = sp[wv][e * 4 + hd];
            const ushort4 hv = *(const ushort4*)&h1[(long)s * 256 + c0];
            acc[0] = fmaf(w, b2f(hv.x), acc[0]);
            acc[1] = fmaf(w, b2f(hv.y), acc[1]);
            acc[2] = fmaf(w, b2f(hv.z), acc[2]);
            acc[3] = fmaf(w, b2f(hv.w), acc[3]);
        }
        __builtin_amdgcn_sched_barrier(0);
        __builtin_amdgcn_wave_barrier();
    }

    #pragma unroll
    for (int off = 1; off < 64; off <<= 1) {
        #pragma unroll
        for (int h = 0; h < 4; ++h) psum[h] += __shfl_xor(psum[h], off);
    }
    const float invd = 1.0f / psum[hd];

    ushort4 o;
    float v;
    v = acc[0] * invd + b1[c0 + 0]; o.x = f2b(v > 0.f ? v : (__expf(v) - 1.0f));
    v = acc[1] * invd + b1[c0 + 1]; o.y = f2b(v > 0.f ? v : (__expf(v) - 1.0f));
    v = acc[2] * invd + b1[c0 + 2]; o.z = f2b(v > 0.f ? v : (__expf(v) - 1.0f));
    v = acc[3] * invd + b1[c0 + 3]; o.w = f2b(v > 0.f ? v : (__expf(v) - 1.0f));
    *(ushort4*)&out[(long)n * 256 + c0] = o;
}

// conv2: 1 head x 256 ch, +b2, bf16 in/out
__global__ __launch_bounds__(256) void agg2_k(
    const unsigned short* __restrict__ h2, const float* __restrict__ as2,
    const float* __restrict__ ad2, const int* __restrict__ indptr,
    const int* __restrict__ csr, const float* __restrict__ b2,
    unsigned short* __restrict__ outb)
{
    __shared__ int   ssrc[4][64];
    __shared__ float sp[4][64];
    const int wv = threadIdx.x >> 6, lane = threadIdx.x & 63;
    const int n = blockIdx.x * 4 + wv;
    if (n >= N_NODES) return;

    const int beg = indptr[n], end = indptr[n + 1];
    const float adv = ad2[n];
    const int c0 = lane * 4;

    float acc[4] = {0.f, 0.f, 0.f, 0.f};
    float psum = 0.f;

    for (int base = beg; base < end; base += 64) {
        const int cnt = min(64, end - base);
        if (lane < cnt) {
            const int s = csr[base + lane];
            const float p = __expf(lrelu02(as2[s] + adv));
            ssrc[wv][lane] = s;
            sp[wv][lane] = p;
            psum += p;
        }
        asm volatile("s_waitcnt lgkmcnt(0)" ::: "memory");
        __builtin_amdgcn_sched_barrier(0);
        for (int e = 0; e < cnt; ++e) {
            const int s = ssrc[wv][e];
            const float w = sp[wv][e];
            const ushort4 hv = *(const ushort4*)&h2[(long)s * 256 + c0];
            acc[0] = fmaf(w, b2f(hv.x), acc[0]);
            acc[1] = fmaf(w, b2f(hv.y), acc[1]);
            acc[2] = fmaf(w, b2f(hv.z), acc[2]);
            acc[3] = fmaf(w, b2f(hv.w), acc[3]);
        }
        __builtin_amdgcn_sched_barrier(0);
        __builtin_amdgcn_wave_barrier();
    }

    #pragma unroll
    for (int off = 1; off < 64; off <<= 1) psum += __shfl_xor(psum, off);
    const float invd = 1.0f / psum;

    ushort4 o;
    o.x = f2b(acc[0] * invd + b2[c0 + 0]);
    o.y = f2b(acc[1] * invd + b2[c0 + 1]);
    o.z = f2b(acc[2] * invd + b2[c0 + 2]);
    o.w = f2b(acc[3] * invd + b2[c0 + 3]);
    *(ushort4*)&outb[(long)n * 256 + c0] = o;
}

// ---------------------------------------------------------------------------
// gate finalize: g = sigmoid(ghid.gw2 + gb2); hf = (1-g)*x + g*hg  (bf16 out)
// ---------------------------------------------------------------------------
__global__ __launch_bounds__(256) void gatefin_k(
    const unsigned short* __restrict__ ghid, const float* __restrict__ gw2,
    const float* __restrict__ gb2, const float* __restrict__ x,
    const unsigned short* __restrict__ hgb, unsigned short* __restrict__ hfb)
{
    const int wid = threadIdx.x >> 6;
    const int lane = threadIdx.x & 63;
    const int n = blockIdx.x * 4 + wid;
    if (n >= N_NODES) return;
    float s = 0.f;
    #pragma unroll
    for (int q = 0; q < 4; ++q)
        s += b2f(ghid[(long)n * 256 + q * 64 + lane]) * gw2[q * 64 + lane];
    #pragma unroll
    for (int off = 32; off > 0; off >>= 1) s += __shfl_xor(s, off);
    const float g = 1.0f / (1.0f + __expf(-(s + gb2[0])));
    #pragma unroll
    for (int q = 0; q < 4; ++q) {
        const int c = q * 64 + lane;
        const float xv = x[(long)n * 256 + c];
        const float hv = b2f(hgb[(long)n * 256 + c]);
        hfb[(long)n * 256 + c] = f2b((1.0f - g) * xv + g * hv);
    }
}

__global__ __launch_bounds__(256) void outinit_k(float* __restrict__ out, const float* __restrict__ pb2)
{
    const int p = blockIdx.x * 256 + threadIdx.x;
    if (p < NP) out[p] = pb2[0];
}

// ---------------------------------------------------------------------------
extern "C" void kernel_launch(void* const* d_in, const int* in_sizes, int n_in,
                              void* d_out, int out_size, void* d_ws, size_t ws_size,
                              hipStream_t stream)
{
    const float* x   = (const float*)d_in[0];
    const int*   ei  = (const int*)d_in[1];
    const int*   un  = (const int*)d_in[2];
    const int*   vn  = (const int*)d_in[3];
    const float* W1  = (const float*)d_in[4];
    const float* a1s = (const float*)d_in[5];
    const float* a1d = (const float*)d_in[6];
    const float* b1  = (const float*)d_in[7];
    const float* W2  = (const float*)d_in[8];
    const float* a2s = (const float*)d_in[9];
    const float* a2d = (const float*)d_in[10];
    const float* b2  = (const float*)d_in[11];
    const float* gw1 = (const float*)d_in[12];
    const float* gb1 = (const float*)d_in[13];
    const float* gw2 = (const float*)d_in[14];
    const float* gb2 = (const float*)d_in[15];
    const float* pw1 = (const float*)d_in[16];
    const float* pb1 = (const float*)d_in[17];
    const float* pw2 = (const float*)d_in[18];
    const float* pb2 = (const float*)d_in[19];
    float* out = (float*)d_out;

    dim3 b256(256);

    if (ws_size >= 58720256u) {
        // ---------------- big path: Z-decomposed predictor ----------------
        // layout (ushort elems from base):
        // Z[20000][1024] @0 (40.96MB); early phases sub-alloc inside Z:
        //   bufHb@0, hgb@+5.12M, xb@+10.24M (all dead before Z GEMM)
        unsigned short* Z     = (unsigned short*)d_ws;
        unsigned short* bufHb = Z;
        unsigned short* hgb   = Z + 5120000;
        unsigned short* xb    = Z + 10240000;
        unsigned short* hfb   = Z + 20480000;            // hf, 10.24MB
        unsigned short* W1t   = hfb + 5120000;
        unsigned short* W2t   = W1t + 65536;
        unsigned short* gw1t  = W2t + 65536;
        unsigned short* pw1t2 = gw1t + 131072;           // [1024][256]
        float* as1v = (float*)(pw1t2 + 262144);
        float* ad1v = as1v + 80000;
        float* as2v = ad1v + 80000;
        float* ad2v = as2v + 20000;
        int* deg    = (int*)(ad2v + 20000);
        int* indptr = deg + 20000;
        int* pos    = indptr + 20032;
        int* csr    = pos + 20000;

        castx_k<<<5000, b256, 0, stream>>>(x, xb);
        tr_k<<<65536 / 256, b256, 0, stream>>>(W1, W1t, 256, 256);
        tr_k<<<65536 / 256, b256, 0, stream>>>(W2, W2t, 256, 256);
        tr_k<<<131072 / 256, b256, 0, stream>>>(gw1, gw1t, 512, 256);
        tr2_k<<<262144 / 256, b256, 0, stream>>>(pw1, pw1t2);
        deg_init_k<<<(N_NODES + 255) / 256, b256, 0, stream>>>(deg);
        deg_count_k<<<(N_EDGES + 255) / 256, b256, 0, stream>>>(ei, deg);
        scan_k<<<1, 1024, 0, stream>>>(deg, indptr, pos);
        fill_k<<<(EPRIME + 255) / 256, b256, 0, stream>>>(ei, pos, csr);

        // conv1 (h1 result reuses hfb buffer as h1a scratch)
        mgemm_k<0, 0><<<dim3(157, 2), b256, 0, stream>>>(
            xb, nullptr, nullptr, nullptr, W1t, nullptr, nullptr, bufHb, nullptr,
            N_NODES, 256, 256);
        alpha1_k<<<5000, b256, 0, stream>>>(bufHb, a1s, a1d, as1v, ad1v);
        agg1_k<<<5000, b256, 0, stream>>>(bufHb, as1v, ad1v, indptr, csr, b1, hfb);

        // conv2
        mgemm_k<0, 0><<<dim3(157, 2), b256, 0, stream>>>(
            hfb, nullptr, nullptr, nullptr, W2t, nullptr, nullptr, bufHb, nullptr,
            N_NODES, 256, 256);
        alpha2_k<<<5000, b256, 0, stream>>>(bufHb, a2s, a2d, as2v, ad2v);
        agg2_k<<<5000, b256, 0, stream>>>(bufHb, as2v, ad2v, indptr, csr, b2, hgb);

        // gate
        mgemm_k<1, 1><<<dim3(157, 2), b256, 0, stream>>>(
            xb, hgb, nullptr, nullptr, gw1t, gb1, nullptr, bufHb, nullptr,
            N_NODES, 512, 256);
        gatefin_k<<<5000, b256, 0, stream>>>(bufHb, gw2, gb2, x, hgb, hfb);

        // Z = hf @ [pw1_top | pw1_bot]  (overwrites bufHb/hgb/xb region)
        mgemm_k<0, 0><<<dim3(157, 8), b256, 0, stream>>>(
            hfb, nullptr, nullptr, nullptr, pw1t2, nullptr, nullptr, Z, nullptr,
            N_NODES, 256, 1024);

        // pair combine
        pair_k<<<25000, b256, 0, stream>>>(Z, un, vn, pb1, pw2, pb2, out);
        return;
    }

    // ---------------- fallback path (R4, needs ~46MB) ----------------
    unsigned short* bufHb = (unsigned short*)d_ws;
    unsigned short* h1ab  = bufHb + 5120000;
    unsigned short* hgb   = h1ab + 5120000;
    unsigned short* xb    = hgb + 5120000;
    unsigned short* W1t   = xb + 5120000;
    unsigned short* W2t   = W1t + 65536;
    unsigned short* gw1t  = W2t + 65536;
    unsigned short* pw1t  = gw1t + 131072;
    float* as1v = (float*)(pw1t + 262144);
    float* ad1v = as1v + 80000;
    float* as2v = ad1v + 80000;
    float* ad2v = as2v + 20000;
    int* deg    = (int*)(ad2v + 20000);
    int* indptr = deg + 20000;
    int* pos    = indptr + 20032;
    int* csr    = pos + 20000;
    if (ws_size < 46u * 1024u * 1024u) return;

    castx_k<<<5000, b256, 0, stream>>>(x, xb);
    tr_k<<<65536 / 256, b256, 0, stream>>>(W1, W1t, 256, 256);
    tr_k<<<65536 / 256, b256, 0, stream>>>(W2, W2t, 256, 256);
    tr_k<<<131072 / 256, b256, 0, stream>>>(gw1, gw1t, 512, 256);
    tr_k<<<262144 / 256, b256, 0, stream>>>(pw1, pw1t, 512, 512);
    deg_init_k<<<(N_NODES + 255) / 256, b256, 0, stream>>>(deg);
    deg_count_k<<<(N_EDGES + 255) / 256, b256, 0, stream>>>(ei, deg);
    scan_k<<<1, 1024, 0, stream>>>(deg, indptr, pos);
    fill_k<<<(EPRIME + 255) / 256, b256, 0, stream>>>(ei, pos, csr);

    mgemm_k<0, 0><<<dim3(157, 2), b256, 0, stream>>>(
        xb, nullptr, nullptr, nullptr, W1t, nullptr, nullptr, bufHb, nullptr,
        N_NODES, 256, 256);
    alpha1_k<<<5000, b256, 0, stream>>>(bufHb, a1s, a1d, as1v, ad1v);
    agg1_k<<<5000, b256, 0, stream>>>(bufHb, as1v, ad1v, indptr, csr, b1, h1ab);

    mgemm_k<0, 0><<<dim3(157, 2), b256, 0, stream>>>(
        h1ab, nullptr, nullptr, nullptr, W2t, nullptr, nullptr, bufHb, nullptr,
        N_NODES, 256, 256);
    alpha2_k<<<5000, b256, 0, stream>>>(bufHb, a2s, a2d, as2v, ad2v);
    agg2_k<<<5000, b256, 0, stream>>>(bufHb, as2v, ad2v, indptr, csr, b2, hgb);

    mgemm_k<1, 1><<<dim3(157, 2), b256, 0, stream>>>(
        xb, hgb, nullptr, nullptr, gw1t, gb1, nullptr, bufHb, nullptr,
        N_NODES, 512, 256);
    gatefin_k<<<5000, b256, 0, stream>>>(bufHb, gw2, gb2, x, hgb, h1ab);

    outinit_k<<<(NP + 255) / 256, b256, 0, stream>>>(out, pb2);
    mgemm_k<2, 2><<<dim3(782, 4), b256, 0, stream>>>(
        h1ab, nullptr, un, vn, pw1t, pb1, pw2, nullptr, out,
        NP, 512, 512);
}

// Round 6
// 257.116 us; speedup vs baseline: 4.4419x; 1.0272x over previous
//
#include <hip/hip_runtime.h>
#include <math.h>

#define N_NODES 20000
#define N_EDGES 320000
#define EPRIME  (N_EDGES + N_NODES)
#define NP      100000

typedef __bf16 bf16x8 __attribute__((ext_vector_type(8)));
typedef float  f32x4  __attribute__((ext_vector_type(4)));

__device__ __forceinline__ float b2f(unsigned short u) {
    union { float f; unsigned int v; } x; x.v = ((unsigned int)u) << 16; return x.f;
}
__device__ __forceinline__ unsigned short f2b(float f) {
    union { float f; unsigned int v; } x; x.f = f;
    unsigned int r = (x.v + 0x7fffu + ((x.v >> 16) & 1u)) >> 16;
    return (unsigned short)r;
}
__device__ __forceinline__ float lrelu02(float v) { return v > 0.0f ? v : 0.2f * v; }

__device__ __forceinline__ void gload16(const void* g, void* l) {
    __builtin_amdgcn_global_load_lds(
        (const __attribute__((address_space(1))) void*)g,
        (__attribute__((address_space(3))) void*)l, 16, 0, 0);
}

// ---------------------------------------------------------------------------
// bf16 MFMA GEMM, BMx128 tile (BM=128 or 64), BK=32, 4 waves (2x2), dbuf LDS,
// XOR-swizzled LDS chunks (R3; conflict-free, counter-verified). The swizzle
// terms depend only on row bits 1..2, which come from lane>>2 in staging and
// lane>>1 in the read — invariant to BM (wave/j only change row bits >=4).
// EPI: 0 = Cb=bf16(acc); 1 = Cb=bf16(relu(acc+bias)); 2 = outp[row] +=
// sum_col relu(acc+bias)*w2 (atomic dot); 3 = Cb=bf16(acc + (col<512?bias:0)).
// ---------------------------------------------------------------------------
template<int BM, int ASRC, int EPI>
__global__ __launch_bounds__(256) void mgemm_k(
    const unsigned short* __restrict__ A0, const unsigned short* __restrict__ A1,
    const int* __restrict__ idxU, const int* __restrict__ idxV,
    const unsigned short* __restrict__ BT,
    const float* __restrict__ bias, const float* __restrict__ w2,
    unsigned short* __restrict__ Cb, float* __restrict__ outp,
    int M, int K, int Nn)
{
    constexpr int NJA   = BM / 64;   // A staging chunks per thread
    constexpr int MF    = BM / 32;   // M fragments per wave
    constexpr int WROWS = BM / 2;    // rows per wave-half

    __shared__ unsigned short As[2][BM * 32];
    __shared__ unsigned short Bs[2][4096];

    const int tid = threadIdx.x;
    const int wave = tid >> 6, lane = tid & 63;
    const int row0 = blockIdx.x * BM, col0 = blockIdx.y * 128;
    const int ksub = (((lane & 3) ^ ((lane >> 3) & 3)) * 8);

    const unsigned short* aL[NJA];
    const unsigned short* aH[NJA];
    const unsigned short* bP[2];
    #pragma unroll
    for (int j = 0; j < NJA; ++j) {
        const int r = j * 64 + wave * 16 + (lane >> 2);
        int ar = row0 + r; if (ar > M - 1) ar = M - 1;
        if (ASRC == 0)      { aL[j] = A0 + (long)ar * K;  aH[j] = aL[j]; }
        else if (ASRC == 1) { aL[j] = A0 + (long)ar * 256; aH[j] = A1 + (long)ar * 256; }
        else { const int u = idxU[ar], v = idxV[ar];
               aL[j] = A0 + (long)u * 256;  aH[j] = A0 + (long)v * 256; }
    }
    #pragma unroll
    for (int j = 0; j < 2; ++j) {
        const int r = j * 64 + wave * 16 + (lane >> 2);
        bP[j] = BT + (long)(col0 + r) * K;
    }

    const int wm = wave >> 1, wn = wave & 1;
    const int lrow = lane & 15;
    const int lks = ((((lane >> 4) ^ ((lane >> 1) & 3)) & 3) * 8);

    f32x4 acc[MF][4] = {};

    const int nT = K >> 5;
    int buf = 0;

    auto stage = [&](int bi, int t) {
        const int k0 = t << 5;
        #pragma unroll
        for (int j = 0; j < NJA; ++j) {
            const unsigned short* ga;
            if (ASRC == 0) ga = aL[j] + k0 + ksub;
            else ga = (k0 < 256) ? (aL[j] + k0 + ksub) : (aH[j] + (k0 - 256) + ksub);
            const int ci = j * 256 + wave * 64 + lane;
            gload16(ga, &As[bi][ci * 8]);
        }
        #pragma unroll
        for (int j = 0; j < 2; ++j) {
            const int ci = j * 256 + wave * 64 + lane;
            gload16(bP[j] + k0 + ksub, &Bs[bi][ci * 8]);
        }
    };

    stage(0, 0);
    __syncthreads();
    for (int t = 0; t < nT; ++t) {
        if (t + 1 < nT) stage(buf ^ 1, t + 1);
        bf16x8 a[MF], b[4];
        #pragma unroll
        for (int i = 0; i < MF; ++i)
            a[i] = *(const bf16x8*)&As[buf][(wm * WROWS + i * 16 + lrow) * 32 + lks];
        #pragma unroll
        for (int j = 0; j < 4; ++j)
            b[j] = *(const bf16x8*)&Bs[buf][(wn * 64 + j * 16 + lrow) * 32 + lks];
        #pragma unroll
        for (int i = 0; i < MF; ++i)
            #pragma unroll
            for (int j = 0; j < 4; ++j)
                acc[i][j] = __builtin_amdgcn_mfma_f32_16x16x32_bf16(a[i], b[j], acc[i][j], 0, 0, 0);
        __syncthreads();
        buf ^= 1;
    }

    if constexpr (EPI == 0 || EPI == 1 || EPI == 3) {
        #pragma unroll
        for (int i = 0; i < MF; ++i) {
            #pragma unroll
            for (int p = 0; p < 4; ++p) {
                const int row = row0 + wm * WROWS + i * 16 + (lane >> 4) * 4 + p;
                if (row < M) {
                    #pragma unroll
                    for (int j = 0; j < 4; ++j) {
                        const int col = col0 + wn * 64 + j * 16 + (lane & 15);
                        float v = acc[i][j][p];
                        if (EPI == 1) { v += bias[col]; v = v > 0.f ? v : 0.f; }
                        if (EPI == 3) { if (col < 512) v += bias[col]; }
                        Cb[(long)row * Nn + col] = f2b(v);
                    }
                }
            }
        }
    } else {
        float s[MF][4];
        #pragma unroll
        for (int i = 0; i < MF; ++i) {
            #pragma unroll
            for (int p = 0; p < 4; ++p) {
                float t = 0.f;
                #pragma unroll
                for (int j = 0; j < 4; ++j) {
                    const int col = col0 + wn * 64 + j * 16 + (lane & 15);
                    float v = acc[i][j][p] + bias[col];
                    v = v > 0.f ? v : 0.f;
                    t += v * w2[col];
                }
                s[i][p] = t;
            }
        }
        #pragma unroll
        for (int off = 1; off < 16; off <<= 1) {
            #pragma unroll
            for (int i = 0; i < MF; ++i)
                #pragma unroll
                for (int p = 0; p < 4; ++p)
                    s[i][p] += __shfl_xor(s[i][p], off);
        }
        if ((lane & 15) == 0) {
            #pragma unroll
            for (int i = 0; i < MF; ++i)
                #pragma unroll
                for (int p = 0; p < 4; ++p) {
                    const int row = row0 + wm * WROWS + i * 16 + (lane >> 4) * 4 + p;
                    if (row < M) atomicAdd(outp + row, s[i][p]);
                }
        }
    }
}

// ---------------------------------------------------------------------------
// pair combine: out[p] = relu(Zt[u] + Zb[v]) . pw2 + pb2   (pb1 folded into Z)
// Z layout [N_NODES][1024] bf16: cols 0..511 = Zt(+pb1), 512..1023 = Zb.
// ---------------------------------------------------------------------------
__global__ __launch_bounds__(256) void pair_k(
    const unsigned short* __restrict__ Z, const int* __restrict__ un,
    const int* __restrict__ vn, const float* __restrict__ pw2,
    const float* __restrict__ pb2, float* __restrict__ out)
{
    const int wv = threadIdx.x >> 6, lane = threadIdx.x & 63;
    const int p = blockIdx.x * 4 + wv;
    if (p >= NP) return;
    const int u = un[p], v = vn[p];
    const int c0 = lane * 8;
    const uint4 zu = *(const uint4*)&Z[(long)u * 1024 + c0];
    const uint4 zv = *(const uint4*)&Z[(long)v * 1024 + 512 + c0];
    const float4 w2a = *(const float4*)&pw2[c0];
    const float4 w2b = *(const float4*)&pw2[c0 + 4];

    float zt[8], zb[8];
    zt[0] = b2f(zu.x & 0xffff); zt[1] = b2f(zu.x >> 16);
    zt[2] = b2f(zu.y & 0xffff); zt[3] = b2f(zu.y >> 16);
    zt[4] = b2f(zu.z & 0xffff); zt[5] = b2f(zu.z >> 16);
    zt[6] = b2f(zu.w & 0xffff); zt[7] = b2f(zu.w >> 16);
    zb[0] = b2f(zv.x & 0xffff); zb[1] = b2f(zv.x >> 16);
    zb[2] = b2f(zv.y & 0xffff); zb[3] = b2f(zv.y >> 16);
    zb[4] = b2f(zv.z & 0xffff); zb[5] = b2f(zv.z >> 16);
    zb[6] = b2f(zv.w & 0xffff); zb[7] = b2f(zv.w >> 16);

    const float ww[8] = {w2a.x, w2a.y, w2a.z, w2a.w, w2b.x, w2b.y, w2b.z, w2b.w};
    float s = 0.f;
    #pragma unroll
    for (int q = 0; q < 8; ++q) {
        float t = zt[q] + zb[q];
        t = t > 0.f ? t : 0.f;
        s = fmaf(t, ww[q], s);
    }
    #pragma unroll
    for (int off = 1; off < 64; off <<= 1) s += __shfl_xor(s, off);
    if (lane == 0) out[p] = s + pb2[0];
}

// ---------------------------------------------------------------------------
// fused prep: x cast + 4 weight transposes + deg init + gacc zero, by bid range
// ---------------------------------------------------------------------------
__global__ __launch_bounds__(256) void prep_k(
    const float* __restrict__ x, unsigned short* __restrict__ xb,
    const float* __restrict__ W1, unsigned short* __restrict__ W1t,
    const float* __restrict__ W2, unsigned short* __restrict__ W2t,
    const float* __restrict__ gw1, unsigned short* __restrict__ gw1t,
    const float* __restrict__ pw1, unsigned short* __restrict__ pw1t2,
    int* __restrict__ deg, float* __restrict__ gacc)
{
    const int bid = blockIdx.x, tid = threadIdx.x;
    if (bid < 5000) {
        const int id = bid * 256 + tid;
        const float4 v = ((const float4*)x)[id];
        ushort4 o;
        o.x = f2b(v.x); o.y = f2b(v.y); o.z = f2b(v.z); o.w = f2b(v.w);
        ((ushort4*)xb)[id] = o;
    } else if (bid < 5256) {
        const int id = (bid - 5000) * 256 + tid;          // 256x256
        W1t[(id & 255) * 256 + (id >> 8)] = f2b(W1[id]);
    } else if (bid < 5512) {
        const int id = (bid - 5256) * 256 + tid;
        W2t[(id & 255) * 256 + (id >> 8)] = f2b(W2[id]);
    } else if (bid < 6024) {
        const int id = (bid - 5512) * 256 + tid;          // 512x256 (K=512,N=256)
        gw1t[(id & 255) * 512 + (id >> 8)] = f2b(gw1[id]);
    } else if (bid < 7048) {
        const int id = (bid - 6024) * 256 + tid;          // 512x512
        const int r = id >> 9, c = id & 511;
        const int j = (r < 256) ? c : (512 + c);
        const int k = (r < 256) ? r : (r - 256);
        pw1t2[j * 256 + k] = f2b(pw1[id]);
    } else if (bid < 7127) {
        const int i = (bid - 7048) * 256 + tid;
        if (i < N_NODES) deg[i] = 1;                      // self-loop
    } else {
        const int i = (bid - 7127) * 256 + tid;
        if (i < N_NODES) gacc[i] = 0.f;
    }
}

// (standalone versions kept for the fallback path)
__global__ __launch_bounds__(256) void castx_k(const float* __restrict__ x,
                                               unsigned short* __restrict__ xb)
{
    const int id = blockIdx.x * 256 + threadIdx.x;
    const float4 v = ((const float4*)x)[id];
    ushort4 o;
    o.x = f2b(v.x); o.y = f2b(v.y); o.z = f2b(v.z); o.w = f2b(v.w);
    ((ushort4*)xb)[id] = o;
}

__global__ __launch_bounds__(256) void tr_k(const float* __restrict__ B,
                                            unsigned short* __restrict__ BT,
                                            int K, int N)
{
    const int id = blockIdx.x * 256 + threadIdx.x;
    const int k = id / N, n = id % N;
    BT[(long)n * K + k] = f2b(B[id]);
}

// ---------------------------------------------------------------------------
// alpha kernels (bf16 h inputs)
// ---------------------------------------------------------------------------
__global__ __launch_bounds__(256) void alpha1_k(
    const unsigned short* __restrict__ h1, const float* __restrict__ a1s,
    const float* __restrict__ a1d, float* __restrict__ as1, float* __restrict__ ad1)
{
    const int wid = threadIdx.x >> 6;
    const int lane = threadIdx.x & 63;
    const int n = blockIdx.x * 4 + wid;
    if (n >= N_NODES) return;
    float ps[4], pd[4];
    #pragma unroll
    for (int h = 0; h < 4; ++h) {
        const float hv = b2f(h1[(long)n * 256 + h * 64 + lane]);
        ps[h] = hv * a1s[h * 64 + lane];
        pd[h] = hv * a1d[h * 64 + lane];
    }
    #pragma unroll
    for (int off = 32; off > 0; off >>= 1) {
        #pragma unroll
        for (int h = 0; h < 4; ++h) {
            ps[h] += __shfl_xor(ps[h], off);
            pd[h] += __shfl_xor(pd[h], off);
        }
    }
    if (lane == 0) {
        #pragma unroll
        for (int h = 0; h < 4; ++h) {
            as1[n * 4 + h] = ps[h];
            ad1[n * 4 + h] = pd[h];
        }
    }
}

__global__ __launch_bounds__(256) void alpha2_k(
    const unsigned short* __restrict__ h2, const float* __restrict__ a2s,
    const float* __restrict__ a2d, float* __restrict__ as2, float* __restrict__ ad2)
{
    const int wid = threadIdx.x >> 6;
    const int lane = threadIdx.x & 63;
    const int n = blockIdx.x * 4 + wid;
    if (n >= N_NODES) return;
    float ps = 0.f, pd = 0.f;
    #pragma unroll
    for (int q = 0; q < 4; ++q) {
        const float hv = b2f(h2[(long)n * 256 + q * 64 + lane]);
        ps += hv * a2s[q * 64 + lane];
        pd += hv * a2d[q * 64 + lane];
    }
    #pragma unroll
    for (int off = 32; off > 0; off >>= 1) {
        ps += __shfl_xor(ps, off);
        pd += __shfl_xor(pd, off);
    }
    if (lane == 0) { as2[n] = ps; ad2[n] = pd; }
}

// ---------------------------------------------------------------------------
// CSR construction (by dst, self-loops via deg init = 1)
// ---------------------------------------------------------------------------
__global__ __launch_bounds__(256) void deg_init_k(int* __restrict__ deg)
{
    const int i = blockIdx.x * 256 + threadIdx.x;
    if (i < N_NODES) deg[i] = 1;
}

__global__ __launch_bounds__(256) void deg_count_k(const int* __restrict__ ei, int* __restrict__ deg)
{
    const int e = blockIdx.x * 256 + threadIdx.x;
    if (e < N_EDGES) atomicAdd(&deg[ei[N_EDGES + e]], 1);
}

__global__ __launch_bounds__(1024) void scan_k(const int* __restrict__ deg,
                                               int* __restrict__ indptr,
                                               int* __restrict__ pos)
{
    __shared__ int sums[1024];
    const int tid = threadIdx.x;
    const int CH = 20;
    const int start = tid * CH;
    const int end = min(start + CH, N_NODES);
    int s = 0;
    for (int i = start; i < end; ++i) s += deg[i];
    sums[tid] = s;
    __syncthreads();
    for (int off = 1; off < 1024; off <<= 1) {
        const int v = sums[tid];
        const int add = (tid >= off) ? sums[tid - off] : 0;
        __syncthreads();
        sums[tid] = v + add;
        __syncthreads();
    }
    int pre = sums[tid] - s;
    for (int i = start; i < end; ++i) {
        indptr[i] = pre;
        pos[i] = pre;
        pre += deg[i];
    }
    if (tid == 1023) indptr[N_NODES] = sums[1023];
}

__global__ __launch_bounds__(256) void fill_k(const int* __restrict__ ei,
                                              int* __restrict__ pos, int* __restrict__ csr)
{
    const int i = blockIdx.x * 256 + threadIdx.x;
    if (i < N_EDGES) {
        const int s = ei[i], d = ei[N_EDGES + i];
        const int p = atomicAdd(&pos[d], 1);
        csr[p] = s;
    } else if (i < EPRIME) {
        const int n = i - N_EDGES;
        const int p = atomicAdd(&pos[n], 1);
        csr[p] = n;
    }
}

// ---------------------------------------------------------------------------
// Fused GAT aggregation conv1: one wave per node, single pass.
// ---------------------------------------------------------------------------
__global__ __launch_bounds__(256) void agg1_k(
    const unsigned short* __restrict__ h1, const float* __restrict__ as1,
    const float* __restrict__ ad1, const int* __restrict__ indptr,
    const int* __restrict__ csr, const float* __restrict__ b1,
    unsigned short* __restrict__ out)
{
    __shared__ int   ssrc[4][64];
    __shared__ float sp[4][64 * 4];
    const int wv = threadIdx.x >> 6, lane = threadIdx.x & 63;
    const int n = blockIdx.x * 4 + wv;
    if (n >= N_NODES) return;

    const int beg = indptr[n], end = indptr[n + 1];
    const float4 ad = ((const float4*)ad1)[n];
    const int c0 = lane * 4;
    const int hd = lane >> 4;

    float acc[4] = {0.f, 0.f, 0.f, 0.f};
    float psum[4] = {0.f, 0.f, 0.f, 0.f};

    for (int base = beg; base < end; base += 64) {
        const int cnt = min(64, end - base);
        if (lane < cnt) {
            const int s = csr[base + lane];
            const float4 av = ((const float4*)as1)[s];
            float4 p;
            p.x = __expf(lrelu02(av.x + ad.x));
            p.y = __expf(lrelu02(av.y + ad.y));
            p.z = __expf(lrelu02(av.z + ad.z));
            p.w = __expf(lrelu02(av.w + ad.w));
            ssrc[wv][lane] = s;
            *(float4*)&sp[wv][lane * 4] = p;
            psum[0] += p.x; psum[1] += p.y; psum[2] += p.z; psum[3] += p.w;
        }
        asm volatile("s_waitcnt lgkmcnt(0)" ::: "memory");
        __builtin_amdgcn_sched_barrier(0);
        for (int e = 0; e < cnt; ++e) {
            const int s = ssrc[wv][e];
            const float w = sp[wv][e * 4 + hd];
            const ushort4 hv = *(const ushort4*)&h1[(long)s * 256 + c0];
            acc[0] = fmaf(w, b2f(hv.x), acc[0]);
            acc[1] = fmaf(w, b2f(hv.y), acc[1]);
            acc[2] = fmaf(w, b2f(hv.z), acc[2]);
            acc[3] = fmaf(w, b2f(hv.w), acc[3]);
        }
        __builtin_amdgcn_sched_barrier(0);
        __builtin_amdgcn_wave_barrier();
    }

    #pragma unroll
    for (int off = 1; off < 64; off <<= 1) {
        #pragma unroll
        for (int h = 0; h < 4; ++h) psum[h] += __shfl_xor(psum[h], off);
    }
    const float invd = 1.0f / psum[hd];

    ushort4 o;
    float v;
    v = acc[0] * invd + b1[c0 + 0]; o.x = f2b(v > 0.f ? v : (__expf(v) - 1.0f));
    v = acc[1] * invd + b1[c0 + 1]; o.y = f2b(v > 0.f ? v : (__expf(v) - 1.0f));
    v = acc[2] * invd + b1[c0 + 2]; o.z = f2b(v > 0.f ? v : (__expf(v) - 1.0f));
    v = acc[3] * invd + b1[c0 + 3]; o.w = f2b(v > 0.f ? v : (__expf(v) - 1.0f));
    *(ushort4*)&out[(long)n * 256 + c0] = o;
}

// conv2: 1 head x 256 ch, +b2, bf16 in/out
__global__ __launch_bounds__(256) void agg2_k(
    const unsigned short* __restrict__ h2, const float* __restrict__ as2,
    const float* __restrict__ ad2, const int* __restrict__ indptr,
    const int* __restrict__ csr, const float* __restrict__ b2,
    unsigned short* __restrict__ outb)
{
    __shared__ int   ssrc[4][64];
    __shared__ float sp[4][64];
    const int wv = threadIdx.x >> 6, lane = threadIdx.x & 63;
    const int n = blockIdx.x * 4 + wv;
    if (n >= N_NODES) return;

    const int beg = indptr[n], end = indptr[n + 1];
    const float adv = ad2[n];
    const int c0 = lane * 4;

    float acc[4] = {0.f, 0.f, 0.f, 0.f};
    float psum = 0.f;

    for (int base = beg; base < end; base += 64) {
        const int cnt = min(64, end - base);
        if (lane < cnt) {
            const int s = csr[base + lane];
            const float p = __expf(lrelu02(as2[s] + adv));
            ssrc[wv][lane] = s;
            sp[wv][lane] = p;
            psum += p;
        }
        asm volatile("s_waitcnt lgkmcnt(0)" ::: "memory");
        __builtin_amdgcn_sched_barrier(0);
        for (int e = 0; e < cnt; ++e) {
            const int s = ssrc[wv][e];
            const float w = sp[wv][e];
            const ushort4 hv = *(const ushort4*)&h2[(long)s * 256 + c0];
            acc[0] = fmaf(w, b2f(hv.x), acc[0]);
            acc[1] = fmaf(w, b2f(hv.y), acc[1]);
            acc[2] = fmaf(w, b2f(hv.z), acc[2]);
            acc[3] = fmaf(w, b2f(hv.w), acc[3]);
        }
        __builtin_amdgcn_sched_barrier(0);
        __builtin_amdgcn_wave_barrier();
    }

    #pragma unroll
    for (int off = 1; off < 64; off <<= 1) psum += __shfl_xor(psum, off);
    const float invd = 1.0f / psum;

    ushort4 o;
    o.x = f2b(acc[0] * invd + b2[c0 + 0]);
    o.y = f2b(acc[1] * invd + b2[c0 + 1]);
    o.z = f2b(acc[2] * invd + b2[c0 + 2]);
    o.w = f2b(acc[3] * invd + b2[c0 + 3]);
    *(ushort4*)&outb[(long)n * 256 + c0] = o;
}

// ---------------------------------------------------------------------------
// gate finalize from pre-reduced dot: g = sigmoid(gacc[n]+gb2); blend -> hfb
// ---------------------------------------------------------------------------
__global__ __launch_bounds__(256) void gatefin2_k(
    const float* __restrict__ gacc, const float* __restrict__ gb2,
    const float* __restrict__ x, const unsigned short* __restrict__ hgb,
    unsigned short* __restrict__ hfb)
{
    const int wid = threadIdx.x >> 6;
    const int lane = threadIdx.x & 63;
    const int n = blockIdx.x * 4 + wid;
    if (n >= N_NODES) return;
    const float g = 1.0f / (1.0f + __expf(-(gacc[n] + gb2[0])));
    #pragma unroll
    for (int q = 0; q < 4; ++q) {
        const int c = q * 64 + lane;
        const float xv = x[(long)n * 256 + c];
        const float hv = b2f(hgb[(long)n * 256 + c]);
        hfb[(long)n * 256 + c] = f2b((1.0f - g) * xv + g * hv);
    }
}

// gate finalize (fallback path, reads ghid)
__global__ __launch_bounds__(256) void gatefin_k(
    const unsigned short* __restrict__ ghid, const float* __restrict__ gw2,
    const float* __restrict__ gb2, const float* __restrict__ x,
    const unsigned short* __restrict__ hgb, unsigned short* __restrict__ hfb)
{
    const int wid = threadIdx.x >> 6;
    const int lane = threadIdx.x & 63;
    const int n = blockIdx.x * 4 + wid;
    if (n >= N_NODES) return;
    float s = 0.f;
    #pragma unroll
    for (int q = 0; q < 4; ++q)
        s += b2f(ghid[(long)n * 256 + q * 64 + lane]) * gw2[q * 64 + lane];
    #pragma unroll
    for (int off = 32; off > 0; off >>= 1) s += __shfl_xor(s, off);
    const float g = 1.0f / (1.0f + __expf(-(s + gb2[0])));
    #pragma unroll
    for (int q = 0; q < 4; ++q) {
        const int c = q * 64 + lane;
        const float xv = x[(long)n * 256 + c];
        const float hv = b2f(hgb[(long)n * 256 + c]);
        hfb[(long)n * 256 + c] = f2b((1.0f - g) * xv + g * hv);
    }
}

__global__ __launch_bounds__(256) void outinit_k(float* __restrict__ out, const float* __restrict__ pb2)
{
    const int p = blockIdx.x * 256 + threadIdx.x;
    if (p < NP) out[p] = pb2[0];
}

// Z-weight transpose (fallback-size tr for pw1 big path handled in prep_k)
__global__ __launch_bounds__(256) void tr2_k(const float* __restrict__ pw1,
                                             unsigned short* __restrict__ BT2)
{
    const int id = blockIdx.x * 256 + threadIdx.x;
    const int r = id >> 9, c = id & 511;
    const int j = (r < 256) ? c : (512 + c);
    const int k = (r < 256) ? r : (r - 256);
    BT2[j * 256 + k] = f2b(pw1[id]);
}

// ---------------------------------------------------------------------------
extern "C" void kernel_launch(void* const* d_in, const int* in_sizes, int n_in,
                              void* d_out, int out_size, void* d_ws, size_t ws_size,
                              hipStream_t stream)
{
    const float* x   = (const float*)d_in[0];
    const int*   ei  = (const int*)d_in[1];
    const int*   un  = (const int*)d_in[2];
    const int*   vn  = (const int*)d_in[3];
    const float* W1  = (const float*)d_in[4];
    const float* a1s = (const float*)d_in[5];
    const float* a1d = (const float*)d_in[6];
    const float* b1  = (const float*)d_in[7];
    const float* W2  = (const float*)d_in[8];
    const float* a2s = (const float*)d_in[9];
    const float* a2d = (const float*)d_in[10];
    const float* b2  = (const float*)d_in[11];
    const float* gw1 = (const float*)d_in[12];
    const float* gb1 = (const float*)d_in[13];
    const float* gw2 = (const float*)d_in[14];
    const float* gb2 = (const float*)d_in[15];
    const float* pw1 = (const float*)d_in[16];
    const float* pb1 = (const float*)d_in[17];
    const float* pw2 = (const float*)d_in[18];
    const float* pb2 = (const float*)d_in[19];
    float* out = (float*)d_out;

    dim3 b256(256);

    if (ws_size >= 58720256u) {
        // ---------------- big path: Z-decomposed predictor ----------------
        unsigned short* Z     = (unsigned short*)d_ws;
        unsigned short* bufHb = Z;
        unsigned short* hgb   = Z + 5120000;
        unsigned short* xb    = Z + 10240000;
        unsigned short* hfb   = Z + 20480000;
        unsigned short* W1t   = hfb + 5120000;
        unsigned short* W2t   = W1t + 65536;
        unsigned short* gw1t  = W2t + 65536;
        unsigned short* pw1t2 = gw1t + 131072;           // [1024][256]
        float* as1v = (float*)(pw1t2 + 262144);
        float* ad1v = as1v + 80000;
        float* as2v = ad1v + 80000;
        float* ad2v = as2v + 20000;
        int* deg    = (int*)(ad2v + 20000);
        int* indptr = deg + 20000;
        int* pos    = indptr + 20032;
        int* csr    = pos + 20000;
        float* gacc = (float*)(csr + EPRIME);

        prep_k<<<7206, b256, 0, stream>>>(x, xb, W1, W1t, W2, W2t, gw1, gw1t,
                                          pw1, pw1t2, deg, gacc);
        deg_count_k<<<(N_EDGES + 255) / 256, b256, 0, stream>>>(ei, deg);
        scan_k<<<1, 1024, 0, stream>>>(deg, indptr, pos);
        fill_k<<<(EPRIME + 255) / 256, b256, 0, stream>>>(ei, pos, csr);

        // conv1
        mgemm_k<64, 0, 0><<<dim3(313, 2), b256, 0, stream>>>(
            xb, nullptr, nullptr, nullptr, W1t, nullptr, nullptr, bufHb, nullptr,
            N_NODES, 256, 256);
        alpha1_k<<<5000, b256, 0, stream>>>(bufHb, a1s, a1d, as1v, ad1v);
        agg1_k<<<5000, b256, 0, stream>>>(bufHb, as1v, ad1v, indptr, csr, b1, hfb);

        // conv2
        mgemm_k<64, 0, 0><<<dim3(313, 2), b256, 0, stream>>>(
            hfb, nullptr, nullptr, nullptr, W2t, nullptr, nullptr, bufHb, nullptr,
            N_NODES, 256, 256);
        alpha2_k<<<5000, b256, 0, stream>>>(bufHb, a2s, a2d, as2v, ad2v);
        agg2_k<<<5000, b256, 0, stream>>>(bufHb, as2v, ad2v, indptr, csr, b2, hgb);

        // gate: atomic dot epilogue, no ghid materialization
        mgemm_k<64, 1, 2><<<dim3(313, 2), b256, 0, stream>>>(
            xb, hgb, nullptr, nullptr, gw1t, gb1, gw2, nullptr, gacc,
            N_NODES, 512, 256);
        gatefin2_k<<<5000, b256, 0, stream>>>(gacc, gb2, x, hgb, hfb);

        // Z = hf @ [pw1_top | pw1_bot] (+pb1 on cols<512)
        mgemm_k<128, 0, 3><<<dim3(157, 8), b256, 0, stream>>>(
            hfb, nullptr, nullptr, nullptr, pw1t2, pb1, nullptr, Z, nullptr,
            N_NODES, 256, 1024);

        pair_k<<<25000, b256, 0, stream>>>(Z, un, vn, pw2, pb2, out);
        return;
    }

    // ---------------- fallback path (R4 structure, ~46MB) ----------------
    unsigned short* bufHb = (unsigned short*)d_ws;
    unsigned short* h1ab  = bufHb + 5120000;
    unsigned short* hgb   = h1ab + 5120000;
    unsigned short* xb    = hgb + 5120000;
    unsigned short* W1t   = xb + 5120000;
    unsigned short* W2t   = W1t + 65536;
    unsigned short* gw1t  = W2t + 65536;
    unsigned short* pw1t  = gw1t + 131072;
    float* as1v = (float*)(pw1t + 262144);
    float* ad1v = as1v + 80000;
    float* as2v = ad1v + 80000;
    float* ad2v = as2v + 20000;
    int* deg    = (int*)(ad2v + 20000);
    int* indptr = deg + 20000;
    int* pos    = indptr + 20032;
    int* csr    = pos + 20000;
    if (ws_size < 46u * 1024u * 1024u) return;

    castx_k<<<5000, b256, 0, stream>>>(x, xb);
    tr_k<<<65536 / 256, b256, 0, stream>>>(W1, W1t, 256, 256);
    tr_k<<<65536 / 256, b256, 0, stream>>>(W2, W2t, 256, 256);
    tr_k<<<131072 / 256, b256, 0, stream>>>(gw1, gw1t, 512, 256);
    tr_k<<<262144 / 256, b256, 0, stream>>>(pw1, pw1t, 512, 512);
    deg_init_k<<<(N_NODES + 255) / 256, b256, 0, stream>>>(deg);
    deg_count_k<<<(N_EDGES + 255) / 256, b256, 0, stream>>>(ei, deg);
    scan_k<<<1, 1024, 0, stream>>>(deg, indptr, pos);
    fill_k<<<(EPRIME + 255) / 256, b256, 0, stream>>>(ei, pos, csr);

    mgemm_k<128, 0, 0><<<dim3(157, 2), b256, 0, stream>>>(
        xb, nullptr, nullptr, nullptr, W1t, nullptr, nullptr, bufHb, nullptr,
        N_NODES, 256, 256);
    alpha1_k<<<5000, b256, 0, stream>>>(bufHb, a1s, a1d, as1v, ad1v);
    agg1_k<<<5000, b256, 0, stream>>>(bufHb, as1v, ad1v, indptr, csr, b1, h1ab);

    mgemm_k<128, 0, 0><<<dim3(157, 2), b256, 0, stream>>>(
        h1ab, nullptr, nullptr, nullptr, W2t, nullptr, nullptr, bufHb, nullptr,
        N_NODES, 256, 256);
    alpha2_k<<<5000, b256, 0, stream>>>(bufHb, a2s, a2d, as2v, ad2v);
    agg2_k<<<5000, b256, 0, stream>>>(bufHb, as2v, ad2v, indptr, csr, b2, hgb);

    mgemm_k<128, 1, 1><<<dim3(157, 2), b256, 0, stream>>>(
        xb, hgb, nullptr, nullptr, gw1t, gb1, nullptr, bufHb, nullptr,
        N_NODES, 512, 256);
    gatefin_k<<<5000, b256, 0, stream>>>(bufHb, gw2, gb2, x, hgb, h1ab);

    outinit_k<<<(NP + 255) / 256, b256, 0, stream>>>(out, pb2);
    mgemm_k<128, 2, 2><<<dim3(782, 4), b256, 0, stream>>>(
        h1ab, nullptr, un, vn, pw1t, pb1, pw2, nullptr, out,
        NP, 512, 512);
}

// Round 7
// 247.835 us; speedup vs baseline: 4.6082x; 1.0374x over previous
//
#include <hip/hip_runtime.h>
#include <math.h>

#define N_NODES 20000
#define N_EDGES 320000
#define EPRIME  (N_EDGES + N_NODES)
#define NP      100000

typedef __bf16 bf16x8 __attribute__((ext_vector_type(8)));
typedef float  f32x4  __attribute__((ext_vector_type(4)));

__device__ __forceinline__ float b2f(unsigned short u) {
    union { float f; unsigned int v; } x; x.v = ((unsigned int)u) << 16; return x.f;
}
__device__ __forceinline__ unsigned short f2b(float f) {
    union { float f; unsigned int v; } x; x.f = f;
    unsigned int r = (x.v + 0x7fffu + ((x.v >> 16) & 1u)) >> 16;
    return (unsigned short)r;
}
__device__ __forceinline__ float lrelu02(float v) { return v > 0.0f ? v : 0.2f * v; }

__device__ __forceinline__ void gload16(const void* g, void* l) {
    __builtin_amdgcn_global_load_lds(
        (const __attribute__((address_space(1))) void*)g,
        (__attribute__((address_space(3))) void*)l, 16, 0, 0);
}

// ---------------------------------------------------------------------------
// bf16 MFMA GEMM, BMx128 tile, BK=32, 4 waves (2x2), dbuf LDS, XOR-swizzled
// LDS chunks (R3; conflict-free, counter-verified).
// EPI: 0 = Cb=bf16(acc); 1 = Cb=bf16(relu(acc+bias));
//      2 = outp[row] += sum_col relu(acc+bias)*w2 (atomic dot)
// ---------------------------------------------------------------------------
template<int BM, int ASRC, int EPI>
__global__ __launch_bounds__(256) void mgemm_k(
    const unsigned short* __restrict__ A0, const unsigned short* __restrict__ A1,
    const unsigned short* __restrict__ BT,
    const float* __restrict__ bias, const float* __restrict__ w2,
    unsigned short* __restrict__ Cb, float* __restrict__ outp,
    int M, int K, int Nn)
{
    constexpr int NJA   = BM / 64;
    constexpr int MF    = BM / 32;
    constexpr int WROWS = BM / 2;

    __shared__ unsigned short As[2][BM * 32];
    __shared__ unsigned short Bs[2][4096];

    const int tid = threadIdx.x;
    const int wave = tid >> 6, lane = tid & 63;
    const int row0 = blockIdx.x * BM, col0 = blockIdx.y * 128;
    const int ksub = (((lane & 3) ^ ((lane >> 3) & 3)) * 8);

    const unsigned short* aL[NJA];
    const unsigned short* aH[NJA];
    const unsigned short* bP[2];
    #pragma unroll
    for (int j = 0; j < NJA; ++j) {
        const int r = j * 64 + wave * 16 + (lane >> 2);
        int ar = row0 + r; if (ar > M - 1) ar = M - 1;
        if (ASRC == 0) { aL[j] = A0 + (long)ar * K;  aH[j] = aL[j]; }
        else           { aL[j] = A0 + (long)ar * 256; aH[j] = A1 + (long)ar * 256; }
    }
    #pragma unroll
    for (int j = 0; j < 2; ++j) {
        const int r = j * 64 + wave * 16 + (lane >> 2);
        bP[j] = BT + (long)(col0 + r) * K;
    }

    const int wm = wave >> 1, wn = wave & 1;
    const int lrow = lane & 15;
    const int lks = ((((lane >> 4) ^ ((lane >> 1) & 3)) & 3) * 8);

    f32x4 acc[MF][4] = {};

    const int nT = K >> 5;
    int buf = 0;

    auto stage = [&](int bi, int t) {
        const int k0 = t << 5;
        #pragma unroll
        for (int j = 0; j < NJA; ++j) {
            const unsigned short* ga;
            if (ASRC == 0) ga = aL[j] + k0 + ksub;
            else ga = (k0 < 256) ? (aL[j] + k0 + ksub) : (aH[j] + (k0 - 256) + ksub);
            const int ci = j * 256 + wave * 64 + lane;
            gload16(ga, &As[bi][ci * 8]);
        }
        #pragma unroll
        for (int j = 0; j < 2; ++j) {
            const int ci = j * 256 + wave * 64 + lane;
            gload16(bP[j] + k0 + ksub, &Bs[bi][ci * 8]);
        }
    };

    stage(0, 0);
    __syncthreads();
    for (int t = 0; t < nT; ++t) {
        if (t + 1 < nT) stage(buf ^ 1, t + 1);
        bf16x8 a[MF], b[4];
        #pragma unroll
        for (int i = 0; i < MF; ++i)
            a[i] = *(const bf16x8*)&As[buf][(wm * WROWS + i * 16 + lrow) * 32 + lks];
        #pragma unroll
        for (int j = 0; j < 4; ++j)
            b[j] = *(const bf16x8*)&Bs[buf][(wn * 64 + j * 16 + lrow) * 32 + lks];
        #pragma unroll
        for (int i = 0; i < MF; ++i)
            #pragma unroll
            for (int j = 0; j < 4; ++j)
                acc[i][j] = __builtin_amdgcn_mfma_f32_16x16x32_bf16(a[i], b[j], acc[i][j], 0, 0, 0);
        __syncthreads();
        buf ^= 1;
    }

    if constexpr (EPI == 0 || EPI == 1) {
        #pragma unroll
        for (int i = 0; i < MF; ++i) {
            #pragma unroll
            for (int p = 0; p < 4; ++p) {
                const int row = row0 + wm * WROWS + i * 16 + (lane >> 4) * 4 + p;
                if (row < M) {
                    #pragma unroll
                    for (int j = 0; j < 4; ++j) {
                        const int col = col0 + wn * 64 + j * 16 + (lane & 15);
                        float v = acc[i][j][p];
                        if (EPI == 1) { v += bias[col]; v = v > 0.f ? v : 0.f; }
                        Cb[(long)row * Nn + col] = f2b(v);
                    }
                }
            }
        }
    } else {
        float s[MF][4];
        #pragma unroll
        for (int i = 0; i < MF; ++i) {
            #pragma unroll
            for (int p = 0; p < 4; ++p) {
                float t = 0.f;
                #pragma unroll
                for (int j = 0; j < 4; ++j) {
                    const int col = col0 + wn * 64 + j * 16 + (lane & 15);
                    float v = acc[i][j][p] + bias[col];
                    v = v > 0.f ? v : 0.f;
                    t += v * w2[col];
                }
                s[i][p] = t;
            }
        }
        #pragma unroll
        for (int off = 1; off < 16; off <<= 1) {
            #pragma unroll
            for (int i = 0; i < MF; ++i)
                #pragma unroll
                for (int p = 0; p < 4; ++p)
                    s[i][p] += __shfl_xor(s[i][p], off);
        }
        if ((lane & 15) == 0) {
            #pragma unroll
            for (int i = 0; i < MF; ++i)
                #pragma unroll
                for (int p = 0; p < 4; ++p) {
                    const int row = row0 + wm * WROWS + i * 16 + (lane >> 4) * 4 + p;
                    if (row < M) atomicAdd(outp + row, s[i][p]);
                }
        }
    }
}

// ---------------------------------------------------------------------------
// Z-GEMM: 128x256 tile, 8 waves (2x4), BK=32, K=256, Nn=1024.
// Z = hf @ [pw1_top | pw1_bot], +pb1 on cols<512. Same swizzle algebra:
// staging row bits 1..2 = (tid>>3)&3 (row = tid>>2 [+128j for B]); read row
// bits 1..2 = (lane>>1)&3. A staged 4x (vs 8x at BN=128), half the blocks.
// ---------------------------------------------------------------------------
__global__ __launch_bounds__(512) void zgemm_k(
    const unsigned short* __restrict__ A0,   // hf  [N_NODES][256]
    const unsigned short* __restrict__ BT,   // pw1t2 [1024][256]
    const float* __restrict__ bias,          // pb1 (512)
    unsigned short* __restrict__ Cb,         // Z [N_NODES][1024]
    int M)
{
    __shared__ unsigned short As[2][4096];   // 128 x 32
    __shared__ unsigned short Bs[2][8192];   // 256 x 32

    const int tid = threadIdx.x;
    const int wave = tid >> 6, lane = tid & 63;
    const int row0 = blockIdx.x * 128, col0 = blockIdx.y * 256;
    const int ksub = (((tid & 3) ^ ((tid >> 3) & 3)) * 8);

    const unsigned short* aP;
    {
        int ar = row0 + (tid >> 2); if (ar > M - 1) ar = M - 1;
        aP = A0 + (long)ar * 256;
    }
    const unsigned short* bP[2];
    #pragma unroll
    for (int j = 0; j < 2; ++j)
        bP[j] = BT + (long)(col0 + j * 128 + (tid >> 2)) * 256;

    const int wm = wave >> 2, wn = wave & 3;
    const int lrow = lane & 15;
    const int lks = ((((lane >> 4) ^ ((lane >> 1) & 3)) & 3) * 8);

    f32x4 acc[4][4] = {};
    int buf = 0;

    auto stage = [&](int bi, int t) {
        const int k0 = t << 5;
        gload16(aP + k0 + ksub, &As[bi][tid * 8]);
        #pragma unroll
        for (int j = 0; j < 2; ++j)
            gload16(bP[j] + k0 + ksub, &Bs[bi][(j * 512 + tid) * 8]);
    };

    stage(0, 0);
    __syncthreads();
    #pragma unroll
    for (int t = 0; t < 8; ++t) {
        if (t + 1 < 8) stage(buf ^ 1, t + 1);
        bf16x8 a[4], b[4];
        #pragma unroll
        for (int i = 0; i < 4; ++i)
            a[i] = *(const bf16x8*)&As[buf][(wm * 64 + i * 16 + lrow) * 32 + lks];
        #pragma unroll
        for (int j = 0; j < 4; ++j)
            b[j] = *(const bf16x8*)&Bs[buf][(wn * 64 + j * 16 + lrow) * 32 + lks];
        #pragma unroll
        for (int i = 0; i < 4; ++i)
            #pragma unroll
            for (int j = 0; j < 4; ++j)
                acc[i][j] = __builtin_amdgcn_mfma_f32_16x16x32_bf16(a[i], b[j], acc[i][j], 0, 0, 0);
        __syncthreads();
        buf ^= 1;
    }

    #pragma unroll
    for (int i = 0; i < 4; ++i) {
        #pragma unroll
        for (int p = 0; p < 4; ++p) {
            const int row = row0 + wm * 64 + i * 16 + (lane >> 4) * 4 + p;
            if (row < M) {
                #pragma unroll
                for (int j = 0; j < 4; ++j) {
                    const int col = col0 + wn * 64 + j * 16 + (lane & 15);
                    float v = acc[i][j][p];
                    if (col < 512) v += bias[col];
                    Cb[(long)row * 1024 + col] = f2b(v);
                }
            }
        }
    }
}

// ---------------------------------------------------------------------------
// pair combine: out[p] = relu(Zt[u] + Zb[v]) . pw2 + pb2   (pb1 folded into Z)
// ---------------------------------------------------------------------------
__global__ __launch_bounds__(256) void pair_k(
    const unsigned short* __restrict__ Z, const int* __restrict__ un,
    const int* __restrict__ vn, const float* __restrict__ pw2,
    const float* __restrict__ pb2, float* __restrict__ out)
{
    const int wv = threadIdx.x >> 6, lane = threadIdx.x & 63;
    const int p = blockIdx.x * 4 + wv;
    if (p >= NP) return;
    const int u = un[p], v = vn[p];
    const int c0 = lane * 8;
    const uint4 zu = *(const uint4*)&Z[(long)u * 1024 + c0];
    const uint4 zv = *(const uint4*)&Z[(long)v * 1024 + 512 + c0];
    const float4 w2a = *(const float4*)&pw2[c0];
    const float4 w2b = *(const float4*)&pw2[c0 + 4];

    float zt[8], zb[8];
    zt[0] = b2f(zu.x & 0xffff); zt[1] = b2f(zu.x >> 16);
    zt[2] = b2f(zu.y & 0xffff); zt[3] = b2f(zu.y >> 16);
    zt[4] = b2f(zu.z & 0xffff); zt[5] = b2f(zu.z >> 16);
    zt[6] = b2f(zu.w & 0xffff); zt[7] = b2f(zu.w >> 16);
    zb[0] = b2f(zv.x & 0xffff); zb[1] = b2f(zv.x >> 16);
    zb[2] = b2f(zv.y & 0xffff); zb[3] = b2f(zv.y >> 16);
    zb[4] = b2f(zv.z & 0xffff); zb[5] = b2f(zv.z >> 16);
    zb[6] = b2f(zv.w & 0xffff); zb[7] = b2f(zv.w >> 16);

    const float ww[8] = {w2a.x, w2a.y, w2a.z, w2a.w, w2b.x, w2b.y, w2b.z, w2b.w};
    float s = 0.f;
    #pragma unroll
    for (int q = 0; q < 8; ++q) {
        float t = zt[q] + zb[q];
        t = t > 0.f ? t : 0.f;
        s = fmaf(t, ww[q], s);
    }
    #pragma unroll
    for (int off = 1; off < 64; off <<= 1) s += __shfl_xor(s, off);
    if (lane == 0) out[p] = s + pb2[0];
}

// ---------------------------------------------------------------------------
// fused prep: x cast + 4 weight transposes + deg init + gacc zero
// ---------------------------------------------------------------------------
__global__ __launch_bounds__(256) void prep_k(
    const float* __restrict__ x, unsigned short* __restrict__ xb,
    const float* __restrict__ W1, unsigned short* __restrict__ W1t,
    const float* __restrict__ W2, unsigned short* __restrict__ W2t,
    const float* __restrict__ gw1, unsigned short* __restrict__ gw1t,
    const float* __restrict__ pw1, unsigned short* __restrict__ pw1t2,
    int* __restrict__ deg, float* __restrict__ gacc)
{
    const int bid = blockIdx.x, tid = threadIdx.x;
    if (bid < 5000) {
        const int id = bid * 256 + tid;
        const float4 v = ((const float4*)x)[id];
        ushort4 o;
        o.x = f2b(v.x); o.y = f2b(v.y); o.z = f2b(v.z); o.w = f2b(v.w);
        ((ushort4*)xb)[id] = o;
    } else if (bid < 5256) {
        const int id = (bid - 5000) * 256 + tid;
        W1t[(id & 255) * 256 + (id >> 8)] = f2b(W1[id]);
    } else if (bid < 5512) {
        const int id = (bid - 5256) * 256 + tid;
        W2t[(id & 255) * 256 + (id >> 8)] = f2b(W2[id]);
    } else if (bid < 6024) {
        const int id = (bid - 5512) * 256 + tid;
        gw1t[(id & 255) * 512 + (id >> 8)] = f2b(gw1[id]);
    } else if (bid < 7048) {
        const int id = (bid - 6024) * 256 + tid;
        const int r = id >> 9, c = id & 511;
        const int j = (r < 256) ? c : (512 + c);
        const int k = (r < 256) ? r : (r - 256);
        pw1t2[j * 256 + k] = f2b(pw1[id]);
    } else if (bid < 7127) {
        const int i = (bid - 7048) * 256 + tid;
        if (i < N_NODES) deg[i] = 1;
    } else {
        const int i = (bid - 7127) * 256 + tid;
        if (i < N_NODES) gacc[i] = 0.f;
    }
}

// ---------------------------------------------------------------------------
// alpha kernels
// ---------------------------------------------------------------------------
__global__ __launch_bounds__(256) void alpha1_k(
    const unsigned short* __restrict__ h1, const float* __restrict__ a1s,
    const float* __restrict__ a1d, float* __restrict__ as1, float* __restrict__ ad1)
{
    const int wid = threadIdx.x >> 6;
    const int lane = threadIdx.x & 63;
    const int n = blockIdx.x * 4 + wid;
    if (n >= N_NODES) return;
    float ps[4], pd[4];
    #pragma unroll
    for (int h = 0; h < 4; ++h) {
        const float hv = b2f(h1[(long)n * 256 + h * 64 + lane]);
        ps[h] = hv * a1s[h * 64 + lane];
        pd[h] = hv * a1d[h * 64 + lane];
    }
    #pragma unroll
    for (int off = 32; off > 0; off >>= 1) {
        #pragma unroll
        for (int h = 0; h < 4; ++h) {
            ps[h] += __shfl_xor(ps[h], off);
            pd[h] += __shfl_xor(pd[h], off);
        }
    }
    if (lane == 0) {
        #pragma unroll
        for (int h = 0; h < 4; ++h) {
            as1[n * 4 + h] = ps[h];
            ad1[n * 4 + h] = pd[h];
        }
    }
}

__global__ __launch_bounds__(256) void alpha2_k(
    const unsigned short* __restrict__ h2, const float* __restrict__ a2s,
    const float* __restrict__ a2d, float* __restrict__ as2, float* __restrict__ ad2)
{
    const int wid = threadIdx.x >> 6;
    const int lane = threadIdx.x & 63;
    const int n = blockIdx.x * 4 + wid;
    if (n >= N_NODES) return;
    float ps = 0.f, pd = 0.f;
    #pragma unroll
    for (int q = 0; q < 4; ++q) {
        const float hv = b2f(h2[(long)n * 256 + q * 64 + lane]);
        ps += hv * a2s[q * 64 + lane];
        pd += hv * a2d[q * 64 + lane];
    }
    #pragma unroll
    for (int off = 32; off > 0; off >>= 1) {
        ps += __shfl_xor(ps, off);
        pd += __shfl_xor(pd, off);
    }
    if (lane == 0) { as2[n] = ps; ad2[n] = pd; }
}

// ---------------------------------------------------------------------------
// CSR construction
// ---------------------------------------------------------------------------
__global__ __launch_bounds__(256) void deg_count_k(const int* __restrict__ ei, int* __restrict__ deg)
{
    const int e = blockIdx.x * 256 + threadIdx.x;
    if (e < N_EDGES) atomicAdd(&deg[ei[N_EDGES + e]], 1);
}

__global__ __launch_bounds__(1024) void scan_k(const int* __restrict__ deg,
                                               int* __restrict__ indptr,
                                               int* __restrict__ pos)
{
    __shared__ int sums[1024];
    const int tid = threadIdx.x;
    const int CH = 20;
    const int start = tid * CH;
    const int end = min(start + CH, N_NODES);
    int s = 0;
    for (int i = start; i < end; ++i) s += deg[i];
    sums[tid] = s;
    __syncthreads();
    for (int off = 1; off < 1024; off <<= 1) {
        const int v = sums[tid];
        const int add = (tid >= off) ? sums[tid - off] : 0;
        __syncthreads();
        sums[tid] = v + add;
        __syncthreads();
    }
    int pre = sums[tid] - s;
    for (int i = start; i < end; ++i) {
        indptr[i] = pre;
        pos[i] = pre;
        pre += deg[i];
    }
    if (tid == 1023) indptr[N_NODES] = sums[1023];
}

__global__ __launch_bounds__(256) void fill_k(const int* __restrict__ ei,
                                              int* __restrict__ pos, int* __restrict__ csr)
{
    const int i = blockIdx.x * 256 + threadIdx.x;
    if (i < N_EDGES) {
        const int s = ei[i], d = ei[N_EDGES + i];
        const int p = atomicAdd(&pos[d], 1);
        csr[p] = s;
    } else if (i < EPRIME) {
        const int n = i - N_EDGES;
        const int p = atomicAdd(&pos[n], 1);
        csr[p] = n;
    }
}

// ---------------------------------------------------------------------------
// Fused GAT aggregation conv1: one wave per node, single pass.
// ---------------------------------------------------------------------------
__global__ __launch_bounds__(256) void agg1_k(
    const unsigned short* __restrict__ h1, const float* __restrict__ as1,
    const float* __restrict__ ad1, const int* __restrict__ indptr,
    const int* __restrict__ csr, const float* __restrict__ b1,
    unsigned short* __restrict__ out)
{
    __shared__ int   ssrc[4][64];
    __shared__ float sp[4][64 * 4];
    const int wv = threadIdx.x >> 6, lane = threadIdx.x & 63;
    const int n = blockIdx.x * 4 + wv;
    if (n >= N_NODES) return;

    const int beg = indptr[n], end = indptr[n + 1];
    const float4 ad = ((const float4*)ad1)[n];
    const int c0 = lane * 4;
    const int hd = lane >> 4;

    float acc[4] = {0.f, 0.f, 0.f, 0.f};
    float psum[4] = {0.f, 0.f, 0.f, 0.f};

    for (int base = beg; base < end; base += 64) {
        const int cnt = min(64, end - base);
        if (lane < cnt) {
            const int s = csr[base + lane];
            const float4 av = ((const float4*)as1)[s];
            float4 p;
            p.x = __expf(lrelu02(av.x + ad.x));
            p.y = __expf(lrelu02(av.y + ad.y));
            p.z = __expf(lrelu02(av.z + ad.z));
            p.w = __expf(lrelu02(av.w + ad.w));
            ssrc[wv][lane] = s;
            *(float4*)&sp[wv][lane * 4] = p;
            psum[0] += p.x; psum[1] += p.y; psum[2] += p.z; psum[3] += p.w;
        }
        asm volatile("s_waitcnt lgkmcnt(0)" ::: "memory");
        __builtin_amdgcn_sched_barrier(0);
        for (int e = 0; e < cnt; ++e) {
            const int s = ssrc[wv][e];
            const float w = sp[wv][e * 4 + hd];
            const ushort4 hv = *(const ushort4*)&h1[(long)s * 256 + c0];
            acc[0] = fmaf(w, b2f(hv.x), acc[0]);
            acc[1] = fmaf(w, b2f(hv.y), acc[1]);
            acc[2] = fmaf(w, b2f(hv.z), acc[2]);
            acc[3] = fmaf(w, b2f(hv.w), acc[3]);
        }
        __builtin_amdgcn_sched_barrier(0);
        __builtin_amdgcn_wave_barrier();
    }

    #pragma unroll
    for (int off = 1; off < 64; off <<= 1) {
        #pragma unroll
        for (int h = 0; h < 4; ++h) psum[h] += __shfl_xor(psum[h], off);
    }
    const float invd = 1.0f / psum[hd];

    ushort4 o;
    float v;
    v = acc[0] * invd + b1[c0 + 0]; o.x = f2b(v > 0.f ? v : (__expf(v) - 1.0f));
    v = acc[1] * invd + b1[c0 + 1]; o.y = f2b(v > 0.f ? v : (__expf(v) - 1.0f));
    v = acc[2] * invd + b1[c0 + 2]; o.z = f2b(v > 0.f ? v : (__expf(v) - 1.0f));
    v = acc[3] * invd + b1[c0 + 3]; o.w = f2b(v > 0.f ? v : (__expf(v) - 1.0f));
    *(ushort4*)&out[(long)n * 256 + c0] = o;
}

// conv2: 1 head x 256 ch, +b2
__global__ __launch_bounds__(256) void agg2_k(
    const unsigned short* __restrict__ h2, const float* __restrict__ as2,
    const float* __restrict__ ad2, const int* __restrict__ indptr,
    const int* __restrict__ csr, const float* __restrict__ b2,
    unsigned short* __restrict__ outb)
{
    __shared__ int   ssrc[4][64];
    __shared__ float sp[4][64];
    const int wv = threadIdx.x >> 6, lane = threadIdx.x & 63;
    const int n = blockIdx.x * 4 + wv;
    if (n >= N_NODES) return;

    const int beg = indptr[n], end = indptr[n + 1];
    const float adv = ad2[n];
    const int c0 = lane * 4;

    float acc[4] = {0.f, 0.f, 0.f, 0.f};
    float psum = 0.f;

    for (int base = beg; base < end; base += 64) {
        const int cnt = min(64, end - base);
        if (lane < cnt) {
            const int s = csr[base + lane];
            const float p = __expf(lrelu02(as2[s] + adv));
            ssrc[wv][lane] = s;
            sp[wv][lane] = p;
            psum += p;
        }
        asm volatile("s_waitcnt lgkmcnt(0)" ::: "memory");
        __builtin_amdgcn_sched_barrier(0);
        for (int e = 0; e < cnt; ++e) {
            const int s = ssrc[wv][e];
            const float w = sp[wv][e];
            const ushort4 hv = *(const ushort4*)&h2[(long)s * 256 + c0];
            acc[0] = fmaf(w, b2f(hv.x), acc[0]);
            acc[1] = fmaf(w, b2f(hv.y), acc[1]);
            acc[2] = fmaf(w, b2f(hv.z), acc[2]);
            acc[3] = fmaf(w, b2f(hv.w), acc[3]);
        }
        __builtin_amdgcn_sched_barrier(0);
        __builtin_amdgcn_wave_barrier();
    }

    #pragma unroll
    for (int off = 1; off < 64; off <<= 1) psum += __shfl_xor(psum, off);
    const float invd = 1.0f / psum;

    ushort4 o;
    o.x = f2b(acc[0] * invd + b2[c0 + 0]);
    o.y = f2b(acc[1] * invd + b2[c0 + 1]);
    o.z = f2b(acc[2] * invd + b2[c0 + 2]);
    o.w = f2b(acc[3] * invd + b2[c0 + 3]);
    *(ushort4*)&outb[(long)n * 256 + c0] = o;
}

// ---------------------------------------------------------------------------
// gate finalize from pre-reduced dot: g = sigmoid(gacc[n]+gb2); blend -> hfb
// ---------------------------------------------------------------------------
__global__ __launch_bounds__(256) void gatefin2_k(
    const float* __restrict__ gacc, const float* __restrict__ gb2,
    const float* __restrict__ x, const unsigned short* __restrict__ hgb,
    unsigned short* __restrict__ hfb)
{
    const int wid = threadIdx.x >> 6;
    const int lane = threadIdx.x & 63;
    const int n = blockIdx.x * 4 + wid;
    if (n >= N_NODES) return;
    const float g = 1.0f / (1.0f + __expf(-(gacc[n] + gb2[0])));
    #pragma unroll
    for (int q = 0; q < 4; ++q) {
        const int c = q * 64 + lane;
        const float xv = x[(long)n * 256 + c];
        const float hv = b2f(hgb[(long)n * 256 + c]);
        hfb[(long)n * 256 + c] = f2b((1.0f - g) * xv + g * hv);
    }
}

// ---------------------------------------------------------------------------
extern "C" void kernel_launch(void* const* d_in, const int* in_sizes, int n_in,
                              void* d_out, int out_size, void* d_ws, size_t ws_size,
                              hipStream_t stream)
{
    const float* x   = (const float*)d_in[0];
    const int*   ei  = (const int*)d_in[1];
    const int*   un  = (const int*)d_in[2];
    const int*   vn  = (const int*)d_in[3];
    const float* W1  = (const float*)d_in[4];
    const float* a1s = (const float*)d_in[5];
    const float* a1d = (const float*)d_in[6];
    const float* b1  = (const float*)d_in[7];
    const float* W2  = (const float*)d_in[8];
    const float* a2s = (const float*)d_in[9];
    const float* a2d = (const float*)d_in[10];
    const float* b2  = (const float*)d_in[11];
    const float* gw1 = (const float*)d_in[12];
    const float* gb1 = (const float*)d_in[13];
    const float* gw2 = (const float*)d_in[14];
    const float* gb2 = (const float*)d_in[15];
    const float* pw1 = (const float*)d_in[16];
    const float* pb1 = (const float*)d_in[17];
    const float* pw2 = (const float*)d_in[18];
    const float* pb2 = (const float*)d_in[19];
    float* out = (float*)d_out;

    dim3 b256(256);

    // ws_size measured 256 MiB (R5/R6 poison fills); big path only.
    if (ws_size < 58720256u) return;

    unsigned short* Z     = (unsigned short*)d_ws;
    unsigned short* bufHb = Z;
    unsigned short* hgb   = Z + 5120000;
    unsigned short* xb    = Z + 10240000;
    unsigned short* hfb   = Z + 20480000;
    unsigned short* W1t   = hfb + 5120000;
    unsigned short* W2t   = W1t + 65536;
    unsigned short* gw1t  = W2t + 65536;
    unsigned short* pw1t2 = gw1t + 131072;           // [1024][256]
    float* as1v = (float*)(pw1t2 + 262144);
    float* ad1v = as1v + 80000;
    float* as2v = ad1v + 80000;
    float* ad2v = as2v + 20000;
    int* deg    = (int*)(ad2v + 20000);
    int* indptr = deg + 20000;
    int* pos    = indptr + 20032;
    int* csr    = pos + 20000;
    float* gacc = (float*)(csr + EPRIME);

    prep_k<<<7206, b256, 0, stream>>>(x, xb, W1, W1t, W2, W2t, gw1, gw1t,
                                      pw1, pw1t2, deg, gacc);
    deg_count_k<<<(N_EDGES + 255) / 256, b256, 0, stream>>>(ei, deg);
    scan_k<<<1, 1024, 0, stream>>>(deg, indptr, pos);
    fill_k<<<(EPRIME + 255) / 256, b256, 0, stream>>>(ei, pos, csr);

    // conv1
    mgemm_k<64, 0, 0><<<dim3(313, 2), b256, 0, stream>>>(
        xb, nullptr, W1t, nullptr, nullptr, bufHb, nullptr, N_NODES, 256, 256);
    alpha1_k<<<5000, b256, 0, stream>>>(bufHb, a1s, a1d, as1v, ad1v);
    agg1_k<<<5000, b256, 0, stream>>>(bufHb, as1v, ad1v, indptr, csr, b1, hfb);

    // conv2
    mgemm_k<64, 0, 0><<<dim3(313, 2), b256, 0, stream>>>(
        hfb, nullptr, W2t, nullptr, nullptr, bufHb, nullptr, N_NODES, 256, 256);
    alpha2_k<<<5000, b256, 0, stream>>>(bufHb, a2s, a2d, as2v, ad2v);
    agg2_k<<<5000, b256, 0, stream>>>(bufHb, as2v, ad2v, indptr, csr, b2, hgb);

    // gate: atomic dot epilogue, no ghid materialization
    mgemm_k<64, 1, 2><<<dim3(313, 2), b256, 0, stream>>>(
        xb, hgb, gw1t, gb1, gw2, nullptr, gacc, N_NODES, 512, 256);
    gatefin2_k<<<5000, b256, 0, stream>>>(gacc, gb2, x, hgb, hfb);

    // Z = hf @ [pw1_top | pw1_bot] (+pb1 on cols<512) — 8-wave 128x256 tile
    zgemm_k<<<dim3(157, 4), dim3(512), 0, stream>>>(hfb, pw1t2, pb1, Z, N_NODES);

    pair_k<<<25000, b256, 0, stream>>>(Z, un, vn, pw2, pb2, out);
}